// Round 5
// baseline (7441.595 us; speedup 1.0000x reference)
//
#include <hip/hip_runtime.h>

#define B_ 512
#define S_ 128
#define T_ 128
#define D_ 512
#define V_ 128
#define LDW 72   // 144B row stride -> 2-way LDS bank aliasing on ds_read_b128 (free)

typedef __attribute__((ext_vector_type(8))) short s16x8;
typedef __attribute__((ext_vector_type(4))) short s16x4;
typedef __attribute__((ext_vector_type(4))) float f32x4;

__device__ __forceinline__ float b2f(unsigned short h) {
    union { unsigned int u; float f; } x; x.u = ((unsigned int)h) << 16; return x.f;
}
__device__ __forceinline__ unsigned short f2b(float f) {
    union { float f; unsigned int u; } x; x.f = f;
    unsigned int u = x.u; u += 0x7FFFu + ((u >> 16) & 1u);
    return (unsigned short)(u >> 16);
}
#if __has_builtin(__builtin_amdgcn_rcpf)
__device__ __forceinline__ float rcp_f(float x) { return __builtin_amdgcn_rcpf(x); }
#else
__device__ __forceinline__ float rcp_f(float x) { return 1.0f / x; }
#endif
__device__ __forceinline__ float sigm(float x) { return rcp_f(1.0f + __expf(-x)); }
__device__ __forceinline__ float tanh_fast(float x) {
    float e = __expf(2.0f * fabsf(x));          // e^{2|x|}; inf -> rcp=0 -> 1.0
    float r = 1.0f - 2.0f * rcp_f(e + 1.0f);
    return copysignf(r, x);
}

struct P {
    const int* target;
    const float* E; const float* bv; const float* ba; const float* bout;
    const short* vab;
    const short* ealb; const short* kpb;
    const short* WaT; const short* WehT; const short* WctxT; const short* WoutT;
    const float* bcat;
    short* qbf; short* xeh; short* ctxb; float* gp;
    short* hcbf; short* h2bf; float* cst;
    float* out_logits; float* out_attn;
};

struct AttnS { float scp[4][64]; float wbuf[S_]; float cpart[4][D_]; };
struct PG128 { short As[128][LDW]; short Bs[128][LDW]; };
struct OutS  { short As[64][LDW]; short Bs[128][LDW]; };
union SharedA { AttnS a; PG128 g; OutS o; };

// ---------------- attention: lane-per-s scores + wave0 softmax + ctx ----------------
__device__ __forceinline__ void attn_phase(const P& p, AttnS& sh, int b, int step)
{
    const int t = threadIdx.x, lane = t & 63, wave = t >> 6;
    // scores: wave w -> s-group (w&1), d-half (w>>1); lane = s within group
    {
        const int sg = wave & 1, dh = wave >> 1;
        const int s = sg * 64 + lane;
        const short* kr = p.kpb + ((size_t)b * S_ + s) * D_ + dh * 256;
        const short* qv = p.qbf + (size_t)b * D_ + dh * 256;   // wave-uniform stream
        const short* vv = p.vab + dh * 256;                    // wave-uniform stream
        float acc = 0.f;
        #pragma unroll 4
        for (int i = 0; i < 32; ++i) {
            s16x8 kv = *(const s16x8*)(kr + i * 8);
            s16x8 qk = *(const s16x8*)(qv + i * 8);
            s16x8 vk = *(const s16x8*)(vv + i * 8);
            #pragma unroll
            for (int j = 0; j < 8; ++j)
                acc += tanh_fast(b2f((unsigned short)qk[j]) + b2f((unsigned short)kv[j]))
                       * b2f((unsigned short)vk[j]);
        }
        sh.scp[wave][lane] = acc;
    }
    __syncthreads();
    if (wave == 0) {
        const float bvv = p.bv[0];
        float v0 = sh.scp[0][lane] + sh.scp[2][lane] + bvv;   // s = lane
        float v1 = sh.scp[1][lane] + sh.scp[3][lane] + bvv;   // s = lane + 64
        float m = fmaxf(v0, v1);
        #pragma unroll
        for (int o = 32; o >= 1; o >>= 1) m = fmaxf(m, __shfl_xor(m, o));
        float e0 = __expf(v0 - m), e1 = __expf(v1 - m);
        float su = e0 + e1;
        #pragma unroll
        for (int o = 32; o >= 1; o >>= 1) su += __shfl_xor(su, o);
        float inv = rcp_f(su);
        float w0 = e0 * inv, w1 = e1 * inv;
        sh.wbuf[lane] = w0; sh.wbuf[lane + 64] = w1;
        float* ao = p.out_attn + ((size_t)b * T_ + step) * S_;
        ao[lane] = w0; ao[lane + 64] = w1;
    }
    __syncthreads();
    {
        const int d0 = lane * 8;
        f32x4 aA = {0.f,0.f,0.f,0.f}, aB = {0.f,0.f,0.f,0.f};
        const short* eb = p.ealb + (size_t)b * S_ * D_ + d0;
        #pragma unroll 4
        for (int i = 0; i < 32; ++i) {
            int s = wave * 32 + i;
            float wv = sh.wbuf[s];
            s16x8 ev = *(const s16x8*)(eb + (size_t)s * D_);
            #pragma unroll
            for (int j = 0; j < 4; ++j) aA[j] += wv * b2f((unsigned short)ev[j]);
            #pragma unroll
            for (int j = 0; j < 4; ++j) aB[j] += wv * b2f((unsigned short)ev[4 + j]);
        }
        *(f32x4*)&sh.cpart[wave][d0]     = aA;
        *(f32x4*)&sh.cpart[wave][d0 + 4] = aB;
    }
    __syncthreads();
    {
        int dd = t * 2;
        float v0 = sh.cpart[0][dd]   + sh.cpart[1][dd]   + sh.cpart[2][dd]   + sh.cpart[3][dd];
        float v1 = sh.cpart[0][dd+1] + sh.cpart[1][dd+1] + sh.cpart[2][dd+1] + sh.cpart[3][dd+1];
        short2 o2; o2.x = (short)f2b(v0); o2.y = (short)f2b(v1);
        *(short2*)(p.ctxb + (size_t)b * D_ + dd) = o2;
    }
}

// ---------------- partial gate GEMM 128x128: Gp = [emb,h] @ W_eh^T + bcat (K=1024) ----------------
__device__ __forceinline__ void pgate_phase(const P& p, PG128& sh, int bid2)
{
    const int t = threadIdx.x, lane = t & 63, wave = t >> 6;
    const int wr = wave >> 1, wc = wave & 1;
    const int lrow = lane & 15, kq = lane >> 4;
    const int m0 = (bid2 >> 4) * 128, n0 = (bid2 & 15) * 128;
    const int K = 1024;
    f32x4 acc[4][4] = {};
    for (int k0 = 0; k0 < K; k0 += 64) {
        s16x8 va[4], vb[4];
        #pragma unroll
        for (int r = 0; r < 4; ++r) {
            int idx = r * 256 + t, row = idx >> 3, seg = idx & 7;
            va[r] = *(const s16x8*)(p.xeh  + (size_t)(m0 + row) * K + k0 + seg * 8);
            vb[r] = *(const s16x8*)(p.WehT + (size_t)(n0 + row) * K + k0 + seg * 8);
        }
        __syncthreads();
        #pragma unroll
        for (int r = 0; r < 4; ++r) {
            int idx = r * 256 + t, row = idx >> 3, seg = idx & 7;
            *(s16x8*)(&sh.As[row][seg * 8]) = va[r];
            *(s16x8*)(&sh.Bs[row][seg * 8]) = vb[r];
        }
        __syncthreads();
        #pragma unroll
        for (int kk = 0; kk < 64; kk += 32) {
            s16x8 af[4], bf[4];
            #pragma unroll
            for (int f = 0; f < 4; ++f) {
                af[f] = *(const s16x8*)(&sh.As[wr * 64 + f * 16 + lrow][kk + kq * 8]);
                bf[f] = *(const s16x8*)(&sh.Bs[wc * 64 + f * 16 + lrow][kk + kq * 8]);
            }
            #pragma unroll
            for (int fa = 0; fa < 4; ++fa)
                #pragma unroll
                for (int fb = 0; fb < 4; ++fb)
                    acc[fa][fb] = __builtin_amdgcn_mfma_f32_16x16x32_bf16(af[fa], bf[fb], acc[fa][fb], 0, 0, 0);
        }
    }
    #pragma unroll
    for (int fa = 0; fa < 4; ++fa)
        #pragma unroll
        for (int fb = 0; fb < 4; ++fb) {
            int col = n0 + wc * 64 + fb * 16 + lrow;
            float bvv = p.bcat[col];
            #pragma unroll
            for (int j = 0; j < 4; ++j) {
                int row = m0 + wr * 64 + fa * 16 + kq * 4 + j;
                p.gp[(size_t)row * 2048 + col] = acc[fa][fb][j] + bvv;
            }
        }
}

// ---------------- final gate GEMM (K=512, ctx) + Gp + fused LSTM ----------------
struct GateS { short As[64][LDW]; short Bs[64][LDW]; float gt[64][65]; };

__device__ __forceinline__ void fgate_phase(const P& p, GateS& sh, int bid, int step)
{
    const int t = threadIdx.x, lane = t & 63, wave = t >> 6;
    const int wr = wave >> 1, wc = wave & 1;
    const int lrow = lane & 15, kq = lane >> 4;
    const int srow = t >> 3, sseg = t & 7;
    const int m0 = (bid >> 5) * 64, n0 = (bid & 31) * 64;
    f32x4 acc[2][2] = {};
    for (int k0 = 0; k0 < 512; k0 += 64) {
        s16x8 va0 = *(const s16x8*)(p.ctxb + (size_t)(m0 + srow) * 512 + k0 + sseg * 8);
        s16x8 va1 = *(const s16x8*)(p.ctxb + (size_t)(m0 + srow + 32) * 512 + k0 + sseg * 8);
        s16x8 vb0 = *(const s16x8*)(p.WctxT + (size_t)(n0 + srow) * 512 + k0 + sseg * 8);
        s16x8 vb1 = *(const s16x8*)(p.WctxT + (size_t)(n0 + srow + 32) * 512 + k0 + sseg * 8);
        __syncthreads();
        *(s16x8*)(&sh.As[srow][sseg * 8]) = va0;
        *(s16x8*)(&sh.As[srow + 32][sseg * 8]) = va1;
        *(s16x8*)(&sh.Bs[srow][sseg * 8]) = vb0;
        *(s16x8*)(&sh.Bs[srow + 32][sseg * 8]) = vb1;
        __syncthreads();
        #pragma unroll
        for (int kk = 0; kk < 64; kk += 32) {
            s16x8 af0 = *(const s16x8*)(&sh.As[wr * 32 + lrow][kk + kq * 8]);
            s16x8 af1 = *(const s16x8*)(&sh.As[wr * 32 + 16 + lrow][kk + kq * 8]);
            s16x8 bf0 = *(const s16x8*)(&sh.Bs[wc * 32 + lrow][kk + kq * 8]);
            s16x8 bf1 = *(const s16x8*)(&sh.Bs[wc * 32 + 16 + lrow][kk + kq * 8]);
            acc[0][0] = __builtin_amdgcn_mfma_f32_16x16x32_bf16(af0, bf0, acc[0][0], 0, 0, 0);
            acc[0][1] = __builtin_amdgcn_mfma_f32_16x16x32_bf16(af0, bf1, acc[0][1], 0, 0, 0);
            acc[1][0] = __builtin_amdgcn_mfma_f32_16x16x32_bf16(af1, bf0, acc[1][0], 0, 0, 0);
            acc[1][1] = __builtin_amdgcn_mfma_f32_16x16x32_bf16(af1, bf1, acc[1][1], 0, 0, 0);
        }
    }
    #pragma unroll
    for (int m2 = 0; m2 < 2; ++m2)
        #pragma unroll
        for (int n2 = 0; n2 < 2; ++n2) {
            int cl = wc * 32 + n2 * 16 + lrow;
            #pragma unroll
            for (int j = 0; j < 4; ++j) {
                int rl = wr * 32 + m2 * 16 + kq * 4 + j;
                sh.gt[rl][cl] = acc[m2][n2][j] + p.gp[(size_t)(m0 + rl) * 2048 + n0 + cl];
            }
        }
    __syncthreads();
    const int rl4 = t >> 4, dl = t & 15;
    #pragma unroll
    for (int pass = 0; pass < 4; ++pass) {
        int row = pass * 16 + rl4;
        int b = m0 + row;
        int d = (n0 >> 2) + dl;
        float gi = sh.gt[row][dl * 4 + 0];
        float gf = sh.gt[row][dl * 4 + 1];
        float gg = sh.gt[row][dl * 4 + 2];
        float go = sh.gt[row][dl * 4 + 3];
        float cv = p.cst[(size_t)b * D_ + d];
        float c2 = sigm(gf) * cv + sigm(gi) * tanh_fast(gg);
        float h2 = sigm(go) * tanh_fast(c2);
        p.cst[(size_t)b * D_ + d] = c2;
        p.hcbf[(size_t)b * D_ + d] = (short)f2b(h2 + c2);
        p.h2bf[(size_t)b * D_ + d] = (short)f2b(h2);
        p.xeh[(size_t)b * 1024 + 512 + d] = (short)f2b(h2);
        int tok = p.target[b * T_ + step];
        p.xeh[(size_t)b * 1024 + d] = (short)f2b(p.E[(size_t)tok * D_ + d]);
    }
}

// ---------------- q GEMM 64x32 tiles -> bf16 q ----------------
__device__ __forceinline__ void q_phase(const P& p, OutS& sh, int bid)
{
    const int t = threadIdx.x, lane = t & 63, wave = t >> 6;
    const int lrow = lane & 15, kq = lane >> 4;
    const int srow = t >> 3, sseg = t & 7;
    const int m0 = (bid >> 4) * 64, n0 = (bid & 15) * 32;
    f32x4 acc0 = {}, acc1 = {};
    for (int k0 = 0; k0 < 512; k0 += 64) {
        s16x8 va0 = *(const s16x8*)(p.hcbf + (size_t)(m0 + srow) * 512 + k0 + sseg * 8);
        s16x8 va1 = *(const s16x8*)(p.hcbf + (size_t)(m0 + srow + 32) * 512 + k0 + sseg * 8);
        s16x8 vb0 = *(const s16x8*)(p.WaT + (size_t)(n0 + srow) * 512 + k0 + sseg * 8);
        __syncthreads();
        *(s16x8*)(&sh.As[srow][sseg * 8]) = va0;
        *(s16x8*)(&sh.As[srow + 32][sseg * 8]) = va1;
        if (srow < 32) *(s16x8*)(&sh.Bs[srow][sseg * 8]) = vb0;
        __syncthreads();
        #pragma unroll
        for (int kk = 0; kk < 64; kk += 32) {
            s16x8 af  = *(const s16x8*)(&sh.As[wave * 16 + lrow][kk + kq * 8]);
            s16x8 bf0 = *(const s16x8*)(&sh.Bs[lrow][kk + kq * 8]);
            s16x8 bf1 = *(const s16x8*)(&sh.Bs[16 + lrow][kk + kq * 8]);
            acc0 = __builtin_amdgcn_mfma_f32_16x16x32_bf16(af, bf0, acc0, 0, 0, 0);
            acc1 = __builtin_amdgcn_mfma_f32_16x16x32_bf16(af, bf1, acc1, 0, 0, 0);
        }
    }
    #pragma unroll
    for (int n2 = 0; n2 < 2; ++n2) {
        int col = n0 + n2 * 16 + lrow;
        float bvv = p.ba[col];
        f32x4 av = n2 ? acc1 : acc0;
        #pragma unroll
        for (int j = 0; j < 4; ++j) {
            int row = m0 + wave * 16 + kq * 4 + j;
            p.qbf[(size_t)row * 512 + col] = (short)f2b(av[j] + bvv);
        }
    }
}

// ---------------- out GEMM (M=512,N=128,K=512) + fused log_softmax ----------------
__device__ __forceinline__ void out_phase(const P& p, OutS& sh, int obid, int step)
{
    const int t = threadIdx.x, lane = t & 63, wave = t >> 6;
    const int lrow = lane & 15, kq = lane >> 4;
    const int srow = t >> 3, sseg = t & 7;
    const int m0 = obid * 64;
    f32x4 acc[8] = {};
    for (int k0 = 0; k0 < 512; k0 += 64) {
        s16x8 va0 = *(const s16x8*)(p.h2bf + (size_t)(m0 + srow) * 512 + k0 + sseg * 8);
        s16x8 va1 = *(const s16x8*)(p.h2bf + (size_t)(m0 + srow + 32) * 512 + k0 + sseg * 8);
        s16x8 vb[4];
        #pragma unroll
        for (int p4 = 0; p4 < 4; ++p4)
            vb[p4] = *(const s16x8*)(p.WoutT + (size_t)(srow + p4 * 32) * 512 + k0 + sseg * 8);
        __syncthreads();
        *(s16x8*)(&sh.As[srow][sseg * 8]) = va0;
        *(s16x8*)(&sh.As[srow + 32][sseg * 8]) = va1;
        #pragma unroll
        for (int p4 = 0; p4 < 4; ++p4) *(s16x8*)(&sh.Bs[srow + p4 * 32][sseg * 8]) = vb[p4];
        __syncthreads();
        #pragma unroll
        for (int kk = 0; kk < 64; kk += 32) {
            s16x8 a = *(const s16x8*)(&sh.As[wave * 16 + lrow][kk + kq * 8]);
            #pragma unroll
            for (int f = 0; f < 8; ++f) {
                s16x8 b = *(const s16x8*)(&sh.Bs[f * 16 + lrow][kk + kq * 8]);
                acc[f] = __builtin_amdgcn_mfma_f32_16x16x32_bf16(a, b, acc[f], 0, 0, 0);
            }
        }
    }
    float colb[8];
    #pragma unroll
    for (int f = 0; f < 8; ++f) colb[f] = p.bout[f * 16 + lrow];
    #pragma unroll
    for (int j = 0; j < 4; ++j) {
        float v[8]; float mx = -1e30f;
        #pragma unroll
        for (int f = 0; f < 8; ++f) { v[f] = acc[f][j] + colb[f]; mx = fmaxf(mx, v[f]); }
        #pragma unroll
        for (int o = 1; o < 16; o <<= 1) mx = fmaxf(mx, __shfl_xor(mx, o));
        float sum = 0.f;
        #pragma unroll
        for (int f = 0; f < 8; ++f) sum += __expf(v[f] - mx);
        #pragma unroll
        for (int o = 1; o < 16; o <<= 1) sum += __shfl_xor(sum, o);
        float lse = mx + __logf(sum);
        int row = m0 + wave * 16 + kq * 4 + j;
        float* orow = p.out_logits + ((size_t)row * T_ + step) * V_;
        #pragma unroll
        for (int f = 0; f < 8; ++f) orow[f * 16 + lrow] = v[f] - lse;
    }
}

// ---------------- per-step dispatches ----------------
__global__ __launch_bounds__(256, 2) void kA(P p, int step) {
    __shared__ SharedA sh;
    const int bid = blockIdx.x;
    if (bid < 512)       attn_phase(p, sh.a, bid, step);
    else if (bid < 576)  pgate_phase(p, sh.g, bid - 512);
    else if (step > 0)   out_phase(p, sh.o, bid - 576, step - 1);
}
__global__ __launch_bounds__(256, 2) void kB(P p, int step) {
    __shared__ GateS sh;
    fgate_phase(p, sh, blockIdx.x, step);
}
__global__ __launch_bounds__(256, 2) void kC(P p) {
    __shared__ OutS sh;
    q_phase(p, sh, blockIdx.x);
}
__global__ __launch_bounds__(256, 2) void kOutLast(P p, int step) {
    __shared__ OutS sh;
    out_phase(p, sh, blockIdx.x, step);
}

// ---------------- precompute kernels ----------------
template<bool OUT_BF16>
__global__ __launch_bounds__(256)
void gemm64(const short* __restrict__ A, const short* __restrict__ Bt,
            const float* __restrict__ bias, void* __restrict__ Cp,
            int M, int N, int K)
{
    __shared__ __align__(16) short As[64][LDW];
    __shared__ __align__(16) short Bs[64][LDW];
    const int t = threadIdx.x;
    const int lane = t & 63, wave = t >> 6;
    const int wr = wave >> 1, wc = wave & 1;
    const int lrow = lane & 15, kq = lane >> 4;
    const int m0 = blockIdx.y * 64, n0 = blockIdx.x * 64;
    const int srow = t >> 3, sseg = t & 7;
    f32x4 acc[2][2] = {};
    for (int k0 = 0; k0 < K; k0 += 64) {
        s16x8 va0 = *(const s16x8*)(A + (size_t)(m0 + srow) * K + k0 + sseg * 8);
        s16x8 va1 = *(const s16x8*)(A + (size_t)(m0 + srow + 32) * K + k0 + sseg * 8);
        s16x8 vb0 = *(const s16x8*)(Bt + (size_t)(n0 + srow) * K + k0 + sseg * 8);
        s16x8 vb1 = *(const s16x8*)(Bt + (size_t)(n0 + srow + 32) * K + k0 + sseg * 8);
        __syncthreads();
        *(s16x8*)(&As[srow][sseg * 8]) = va0;
        *(s16x8*)(&As[srow + 32][sseg * 8]) = va1;
        *(s16x8*)(&Bs[srow][sseg * 8]) = vb0;
        *(s16x8*)(&Bs[srow + 32][sseg * 8]) = vb1;
        __syncthreads();
        for (int kk = 0; kk < 64; kk += 32) {
            s16x8 af[2], bf[2];
            af[0] = *(const s16x8*)(&As[wr * 32 + lrow][kk + kq * 8]);
            af[1] = *(const s16x8*)(&As[wr * 32 + 16 + lrow][kk + kq * 8]);
            bf[0] = *(const s16x8*)(&Bs[wc * 32 + lrow][kk + kq * 8]);
            bf[1] = *(const s16x8*)(&Bs[wc * 32 + 16 + lrow][kk + kq * 8]);
            for (int m2 = 0; m2 < 2; ++m2)
                for (int n2 = 0; n2 < 2; ++n2)
                    acc[m2][n2] = __builtin_amdgcn_mfma_f32_16x16x32_bf16(af[m2], bf[n2], acc[m2][n2], 0, 0, 0);
        }
    }
    for (int m2 = 0; m2 < 2; ++m2)
        for (int n2 = 0; n2 < 2; ++n2) {
            int col = n0 + wc * 32 + n2 * 16 + lrow;
            float bvv = bias ? bias[col] : 0.0f;
            for (int j = 0; j < 4; ++j) {
                int row = m0 + wr * 32 + m2 * 16 + kq * 4 + j;
                float v = acc[m2][n2][j] + bvv;
                if (OUT_BF16) ((short*)Cp)[(size_t)row * N + col] = (short)f2b(v);
                else          ((float*)Cp)[(size_t)row * N + col] = v;
            }
        }
}

__global__ __launch_bounds__(256)
void init_state(const float* __restrict__ e_h, const float* __restrict__ e_c,
                float* __restrict__ c, short* __restrict__ hcbf,
                short* __restrict__ xeh, const float* __restrict__ E)
{
    int gid = blockIdx.x * 256 + threadIdx.x;
    int b = gid >> 9, d = gid & 511;
    float h0 = e_h[gid], c0 = e_c[gid];
    c[gid] = c0;
    hcbf[gid] = (short)f2b(h0 + c0);
    xeh[(size_t)b * 1024 + 512 + d] = (short)f2b(h0);
    xeh[(size_t)b * 1024 + d] = (short)f2b(E[d]);   // token 0 (SOS)
}

__global__ __launch_bounds__(256)
void transpose_cast(const float* __restrict__ in, short* __restrict__ out,
                    int N, int ostride, int koff, int gate_perm)
{
    __shared__ float tile[64][65];
    int t = threadIdx.x;
    int n0 = blockIdx.x * 64, k0 = blockIdx.y * 64;
    int cc = t & 63, r4 = t >> 6;
    for (int i = 0; i < 16; ++i) {
        int r = i * 4 + r4;
        tile[r][cc] = in[(size_t)(k0 + r) * N + n0 + cc];
    }
    __syncthreads();
    for (int i = 0; i < 16; ++i) {
        int nr = i * 4 + r4;
        int ng = n0 + nr;
        int np = gate_perm ? ((ng & 511) * 4 + (ng >> 9)) : ng;
        out[(size_t)np * ostride + koff + k0 + cc] = (short)f2b(tile[cc][nr]);
    }
}

__global__ __launch_bounds__(256)
void cast_bf16_v4(const float* __restrict__ in, short* __restrict__ out, int n4)
{
    int i = blockIdx.x * 256 + threadIdx.x;
    int stride = gridDim.x * 256;
    for (; i < n4; i += stride) {
        f32x4 v = ((const f32x4*)in)[i];
        s16x4 o;
        for (int j = 0; j < 4; ++j) o[j] = (short)f2b(v[j]);
        ((s16x4*)out)[i] = o;
    }
}

__global__ __launch_bounds__(256)
void make_bcat(const float* __restrict__ b_ih, const float* __restrict__ b_hh, float* __restrict__ bcat)
{
    int i = blockIdx.x * 256 + threadIdx.x;
    if (i < 2048) {
        int np = (i & 511) * 4 + (i >> 9);
        bcat[np] = b_ih[i] + b_hh[i];
    }
}

extern "C" void kernel_launch(void* const* d_in, const int* in_sizes, int n_in,
                              void* d_out, int out_size, void* d_ws, size_t ws_size,
                              hipStream_t stream)
{
    const float* e_all  = (const float*)d_in[0];
    const float* e_h    = (const float*)d_in[1];
    const float* e_c    = (const float*)d_in[2];
    const int*   target = (const int*)d_in[3];
    const float* E      = (const float*)d_in[4];
    const float* Wa     = (const float*)d_in[5];
    const float* ba     = (const float*)d_in[6];
    const float* Ua     = (const float*)d_in[7];
    const float* bu     = (const float*)d_in[8];
    const float* Va     = (const float*)d_in[9];
    const float* bv     = (const float*)d_in[10];
    const float* W_ih   = (const float*)d_in[11];
    const float* b_ih   = (const float*)d_in[12];
    const float* W_hh   = (const float*)d_in[13];
    const float* b_hh   = (const float*)d_in[14];
    const float* W_out  = (const float*)d_in[15];
    const float* b_out  = (const float*)d_in[16];

    char* ws = (char*)d_ws;
    size_t off = 0;
    auto alloc = [&](size_t bytes) { void* p = ws + off; off += (bytes + 255) & ~255ull; return p; };
    short* ealb  = (short*)alloc((size_t)B_ * S_ * D_ * 2);
    short* kpb   = (short*)alloc((size_t)B_ * S_ * D_ * 2);
    short* WaT   = (short*)alloc((size_t)D_ * D_ * 2);
    short* UaT   = (short*)alloc((size_t)D_ * D_ * 2);
    short* WehT  = (short*)alloc((size_t)2048 * 1024 * 2);
    short* WctxT = (short*)alloc((size_t)2048 * 512 * 2);
    short* WoutT = (short*)alloc((size_t)V_ * D_ * 2);
    float* bcat  = (float*)alloc(2048 * 4);
    short* qbf   = (short*)alloc((size_t)B_ * D_ * 2);
    short* vab   = (short*)alloc((size_t)D_ * 2);
    short* xeh   = (short*)alloc((size_t)B_ * 1024 * 2);
    short* ctxb  = (short*)alloc((size_t)B_ * D_ * 2);
    float* gp    = (float*)alloc((size_t)B_ * 2048 * 4);
    short* hcbf  = (short*)alloc((size_t)B_ * D_ * 2);
    short* h2bf  = (short*)alloc((size_t)B_ * D_ * 2);
    float* cst   = (float*)alloc((size_t)B_ * D_ * 4);
    if (off > ws_size) return;

    float* out_logits = (float*)d_out;                        // [B,T,V]
    float* out_attn   = (float*)d_out + (size_t)B_ * T_ * V_; // [B,T,S]

    // ---- precompute ----
    cast_bf16_v4<<<4096, 256, 0, stream>>>(e_all, ealb, B_ * S_ * D_ / 4);
    cast_bf16_v4<<<1,    256, 0, stream>>>(Va, vab, D_ / 4);
    transpose_cast<<<dim3(8, 8),  256, 0, stream>>>(Wa,  WaT,  512,  512, 0, 0);
    transpose_cast<<<dim3(8, 8),  256, 0, stream>>>(Ua,  UaT,  512,  512, 0, 0);
    transpose_cast<<<dim3(32, 8), 256, 0, stream>>>(W_ih,              WehT,  2048, 1024, 0,   1);
    transpose_cast<<<dim3(32, 8), 256, 0, stream>>>(W_ih + 512 * 2048, WctxT, 2048, 512,  0,   1);
    transpose_cast<<<dim3(32, 8), 256, 0, stream>>>(W_hh,              WehT,  2048, 1024, 512, 1);
    transpose_cast<<<dim3(2, 8),  256, 0, stream>>>(W_out, WoutT, 128, 512, 0, 0);
    make_bcat<<<8, 256, 0, stream>>>(b_ih, b_hh, bcat);
    gemm64<true><<<dim3(8, 1024), 256, 0, stream>>>(ealb, UaT, bu, kpb, B_ * S_, 512, 512);
    init_state<<<1024, 256, 0, stream>>>(e_h, e_c, cst, hcbf, xeh, E);
    gemm64<true><<<dim3(8, 8), 256, 0, stream>>>(hcbf, WaT, ba, qbf, B_, 512, 512);

    P pp;
    pp.target = target; pp.E = E; pp.bv = bv; pp.ba = ba; pp.bout = b_out;
    pp.vab = vab;
    pp.ealb = ealb; pp.kpb = kpb; pp.WaT = WaT; pp.WehT = WehT; pp.WctxT = WctxT; pp.WoutT = WoutT;
    pp.bcat = bcat; pp.qbf = qbf; pp.xeh = xeh; pp.ctxb = ctxb; pp.gp = gp;
    pp.hcbf = hcbf; pp.h2bf = h2bf; pp.cst = cst;
    pp.out_logits = out_logits; pp.out_attn = out_attn;

    // ---- sequential decode: A(attn ∥ partial-gate ∥ out_{t-1}) -> B(final gate+LSTM) -> C(q_{t+1})
    for (int t = 0; t < T_; ++t) {
        kA<<<584, 256, 0, stream>>>(pp, t);
        kB<<<256, 256, 0, stream>>>(pp, t);
        if (t < T_ - 1) kC<<<128, 256, 0, stream>>>(pp);
    }
    kOutLast<<<8, 256, 0, stream>>>(pp, T_ - 1);
    (void)n_in; (void)in_sizes; (void)out_size;
}

// Round 6
// 6630.505 us; speedup vs baseline: 1.1223x; 1.1223x over previous
//
#include <hip/hip_runtime.h>

#define B_ 512
#define S_ 128
#define T_ 128
#define D_ 512
#define V_ 128
#define LDW 72   // 144B row stride -> 2-way LDS bank aliasing on ds_read_b128 (free)

typedef __attribute__((ext_vector_type(8))) short s16x8;
typedef __attribute__((ext_vector_type(4))) short s16x4;
typedef __attribute__((ext_vector_type(4))) float f32x4;

__device__ __forceinline__ float b2f(unsigned short h) {
    union { unsigned int u; float f; } x; x.u = ((unsigned int)h) << 16; return x.f;
}
__device__ __forceinline__ unsigned short f2b(float f) {
    union { float f; unsigned int u; } x; x.f = f;
    unsigned int u = x.u; u += 0x7FFFu + ((u >> 16) & 1u);
    return (unsigned short)(u >> 16);
}
#if __has_builtin(__builtin_amdgcn_rcpf)
__device__ __forceinline__ float rcp_f(float x) { return __builtin_amdgcn_rcpf(x); }
#else
__device__ __forceinline__ float rcp_f(float x) { return 1.0f / x; }
#endif
__device__ __forceinline__ float sigm(float x) { return rcp_f(1.0f + __expf(-x)); }
__device__ __forceinline__ float tanh_fast(float x) {
    float e = __expf(2.0f * fabsf(x));          // e^{2|x|}; inf -> rcp=0 -> 1.0
    float r = 1.0f - 2.0f * rcp_f(e + 1.0f);
    return copysignf(r, x);
}

struct P {
    const int* target;
    const float* E; const float* bv; const float* ba; const float* bout;
    const short* vab;
    const short* ealb; const short* kpb;
    const short* WaT; const short* WehT; const short* WctxT; const short* WoutT;
    const float* bcat;
    short* qbf; short* xeh; short* ctxb; float* gp;
    short* hcbf; short* h2bf; float* cst;
    float* out_logits; float* out_attn;
};

struct AttnS { float scp[4][64]; float wbuf[S_]; float cpart[4][D_]; };
struct OutS  { short As[64][LDW]; short Bs[128][LDW]; };
struct PG2   { short As[128][LDW]; short Bs[64][LDW]; };
struct GateS { short As[64][LDW]; short Bs[64][LDW]; float gt[64][65]; };
union SharedC { OutS o; PG2 g; };

// ---------------- attention: lane-per-s scores + wave0 softmax + ctx ----------------
__device__ __forceinline__ void attn_phase(const P& p, AttnS& sh, int b, int step)
{
    const int t = threadIdx.x, lane = t & 63, wave = t >> 6;
    // scores: wave w -> s-group (w&1), d-half (w>>1); lane = s within group
    {
        const int sg = wave & 1, dh = wave >> 1;
        const int s = sg * 64 + lane;
        const short* kr = p.kpb + ((size_t)b * S_ + s) * D_ + dh * 256;
        const short* qv = p.qbf + (size_t)b * D_ + dh * 256;   // wave-uniform stream
        const short* vv = p.vab + dh * 256;                    // wave-uniform stream
        float acc = 0.f;
        #pragma unroll 4
        for (int i = 0; i < 32; ++i) {
            s16x8 kv = *(const s16x8*)(kr + i * 8);
            s16x8 qk = *(const s16x8*)(qv + i * 8);
            s16x8 vk = *(const s16x8*)(vv + i * 8);
            #pragma unroll
            for (int j = 0; j < 8; ++j)
                acc += tanh_fast(b2f((unsigned short)qk[j]) + b2f((unsigned short)kv[j]))
                       * b2f((unsigned short)vk[j]);
        }
        sh.scp[wave][lane] = acc;
    }
    __syncthreads();
    if (wave == 0) {
        const float bvv = p.bv[0];
        float v0 = sh.scp[0][lane] + sh.scp[2][lane] + bvv;   // s = lane
        float v1 = sh.scp[1][lane] + sh.scp[3][lane] + bvv;   // s = lane + 64
        float m = fmaxf(v0, v1);
        #pragma unroll
        for (int o = 32; o >= 1; o >>= 1) m = fmaxf(m, __shfl_xor(m, o));
        float e0 = __expf(v0 - m), e1 = __expf(v1 - m);
        float su = e0 + e1;
        #pragma unroll
        for (int o = 32; o >= 1; o >>= 1) su += __shfl_xor(su, o);
        float inv = rcp_f(su);
        float w0 = e0 * inv, w1 = e1 * inv;
        sh.wbuf[lane] = w0; sh.wbuf[lane + 64] = w1;
        float* ao = p.out_attn + ((size_t)b * T_ + step) * S_;
        ao[lane] = w0; ao[lane + 64] = w1;
    }
    __syncthreads();
    {
        const int d0 = lane * 8;
        f32x4 aA = {0.f,0.f,0.f,0.f}, aB = {0.f,0.f,0.f,0.f};
        const short* eb = p.ealb + (size_t)b * S_ * D_ + d0;
        #pragma unroll 4
        for (int i = 0; i < 32; ++i) {
            int s = wave * 32 + i;
            float wv = sh.wbuf[s];
            s16x8 ev = *(const s16x8*)(eb + (size_t)s * D_);
            #pragma unroll
            for (int j = 0; j < 4; ++j) aA[j] += wv * b2f((unsigned short)ev[j]);
            #pragma unroll
            for (int j = 0; j < 4; ++j) aB[j] += wv * b2f((unsigned short)ev[4 + j]);
        }
        *(f32x4*)&sh.cpart[wave][d0]     = aA;
        *(f32x4*)&sh.cpart[wave][d0 + 4] = aB;
    }
    __syncthreads();
    {
        int dd = t * 2;
        float v0 = sh.cpart[0][dd]   + sh.cpart[1][dd]   + sh.cpart[2][dd]   + sh.cpart[3][dd];
        float v1 = sh.cpart[0][dd+1] + sh.cpart[1][dd+1] + sh.cpart[2][dd+1] + sh.cpart[3][dd+1];
        short2 o2; o2.x = (short)f2b(v0); o2.y = (short)f2b(v1);
        *(short2*)(p.ctxb + (size_t)b * D_ + dd) = o2;
    }
}

// ---------------- partial gate GEMM 128x64: Gp = [emb,h] @ W_eh^T + bcat (K=1024) ----------------
__device__ __forceinline__ void pgate_phase(const P& p, PG2& sh, int bid2)
{
    const int t = threadIdx.x, lane = t & 63, wave = t >> 6;
    const int lrow = lane & 15, kq = lane >> 4;
    const int m0 = (bid2 >> 5) * 128, n0 = (bid2 & 31) * 64;
    const int K = 1024;
    f32x4 acc[2][4] = {};
    for (int k0 = 0; k0 < K; k0 += 64) {
        s16x8 va[4], vb[2];
        #pragma unroll
        for (int r = 0; r < 4; ++r) {
            int idx = r * 256 + t, row = idx >> 3, seg = idx & 7;
            va[r] = *(const s16x8*)(p.xeh + (size_t)(m0 + row) * K + k0 + seg * 8);
        }
        #pragma unroll
        for (int r = 0; r < 2; ++r) {
            int idx = r * 256 + t, row = idx >> 3, seg = idx & 7;
            vb[r] = *(const s16x8*)(p.WehT + (size_t)(n0 + row) * K + k0 + seg * 8);
        }
        __syncthreads();
        #pragma unroll
        for (int r = 0; r < 4; ++r) {
            int idx = r * 256 + t, row = idx >> 3, seg = idx & 7;
            *(s16x8*)(&sh.As[row][seg * 8]) = va[r];
        }
        #pragma unroll
        for (int r = 0; r < 2; ++r) {
            int idx = r * 256 + t, row = idx >> 3, seg = idx & 7;
            *(s16x8*)(&sh.Bs[row][seg * 8]) = vb[r];
        }
        __syncthreads();
        #pragma unroll
        for (int kk = 0; kk < 64; kk += 32) {
            s16x8 af[2], bf[4];
            af[0] = *(const s16x8*)(&sh.As[wave * 32 + lrow][kk + kq * 8]);
            af[1] = *(const s16x8*)(&sh.As[wave * 32 + 16 + lrow][kk + kq * 8]);
            #pragma unroll
            for (int f = 0; f < 4; ++f)
                bf[f] = *(const s16x8*)(&sh.Bs[f * 16 + lrow][kk + kq * 8]);
            #pragma unroll
            for (int m2 = 0; m2 < 2; ++m2)
                #pragma unroll
                for (int n2 = 0; n2 < 4; ++n2)
                    acc[m2][n2] = __builtin_amdgcn_mfma_f32_16x16x32_bf16(af[m2], bf[n2], acc[m2][n2], 0, 0, 0);
        }
    }
    #pragma unroll
    for (int m2 = 0; m2 < 2; ++m2)
        #pragma unroll
        for (int n2 = 0; n2 < 4; ++n2) {
            int col = n0 + n2 * 16 + lrow;
            float bvv = p.bcat[col];
            #pragma unroll
            for (int j = 0; j < 4; ++j) {
                int row = m0 + wave * 32 + m2 * 16 + kq * 4 + j;
                p.gp[(size_t)row * 2048 + col] = acc[m2][n2][j] + bvv;
            }
        }
}

// ---------------- final gate GEMM (K=512, ctx) + Gp + fused LSTM ----------------
__device__ __forceinline__ void fgate_phase(const P& p, GateS& sh, int bid, int step)
{
    const int t = threadIdx.x, lane = t & 63, wave = t >> 6;
    const int wr = wave >> 1, wc = wave & 1;
    const int lrow = lane & 15, kq = lane >> 4;
    const int srow = t >> 3, sseg = t & 7;
    const int m0 = (bid >> 5) * 64, n0 = (bid & 31) * 64;
    f32x4 acc[2][2] = {};
    for (int k0 = 0; k0 < 512; k0 += 64) {
        s16x8 va0 = *(const s16x8*)(p.ctxb + (size_t)(m0 + srow) * 512 + k0 + sseg * 8);
        s16x8 va1 = *(const s16x8*)(p.ctxb + (size_t)(m0 + srow + 32) * 512 + k0 + sseg * 8);
        s16x8 vb0 = *(const s16x8*)(p.WctxT + (size_t)(n0 + srow) * 512 + k0 + sseg * 8);
        s16x8 vb1 = *(const s16x8*)(p.WctxT + (size_t)(n0 + srow + 32) * 512 + k0 + sseg * 8);
        __syncthreads();
        *(s16x8*)(&sh.As[srow][sseg * 8]) = va0;
        *(s16x8*)(&sh.As[srow + 32][sseg * 8]) = va1;
        *(s16x8*)(&sh.Bs[srow][sseg * 8]) = vb0;
        *(s16x8*)(&sh.Bs[srow + 32][sseg * 8]) = vb1;
        __syncthreads();
        #pragma unroll
        for (int kk = 0; kk < 64; kk += 32) {
            s16x8 af0 = *(const s16x8*)(&sh.As[wr * 32 + lrow][kk + kq * 8]);
            s16x8 af1 = *(const s16x8*)(&sh.As[wr * 32 + 16 + lrow][kk + kq * 8]);
            s16x8 bf0 = *(const s16x8*)(&sh.Bs[wc * 32 + lrow][kk + kq * 8]);
            s16x8 bf1 = *(const s16x8*)(&sh.Bs[wc * 32 + 16 + lrow][kk + kq * 8]);
            acc[0][0] = __builtin_amdgcn_mfma_f32_16x16x32_bf16(af0, bf0, acc[0][0], 0, 0, 0);
            acc[0][1] = __builtin_amdgcn_mfma_f32_16x16x32_bf16(af0, bf1, acc[0][1], 0, 0, 0);
            acc[1][0] = __builtin_amdgcn_mfma_f32_16x16x32_bf16(af1, bf0, acc[1][0], 0, 0, 0);
            acc[1][1] = __builtin_amdgcn_mfma_f32_16x16x32_bf16(af1, bf1, acc[1][1], 0, 0, 0);
        }
    }
    #pragma unroll
    for (int m2 = 0; m2 < 2; ++m2)
        #pragma unroll
        for (int n2 = 0; n2 < 2; ++n2) {
            int cl = wc * 32 + n2 * 16 + lrow;
            #pragma unroll
            for (int j = 0; j < 4; ++j) {
                int rl = wr * 32 + m2 * 16 + kq * 4 + j;
                sh.gt[rl][cl] = acc[m2][n2][j] + p.gp[(size_t)(m0 + rl) * 2048 + n0 + cl];
            }
        }
    __syncthreads();
    const int rl4 = t >> 4, dl = t & 15;
    #pragma unroll
    for (int pass = 0; pass < 4; ++pass) {
        int row = pass * 16 + rl4;
        int b = m0 + row;
        int d = (n0 >> 2) + dl;
        float gi = sh.gt[row][dl * 4 + 0];
        float gf = sh.gt[row][dl * 4 + 1];
        float gg = sh.gt[row][dl * 4 + 2];
        float go = sh.gt[row][dl * 4 + 3];
        float cv = p.cst[(size_t)b * D_ + d];
        float c2 = sigm(gf) * cv + sigm(gi) * tanh_fast(gg);
        float h2 = sigm(go) * tanh_fast(c2);
        p.cst[(size_t)b * D_ + d] = c2;
        p.hcbf[(size_t)b * D_ + d] = (short)f2b(h2 + c2);
        p.h2bf[(size_t)b * D_ + d] = (short)f2b(h2);
        p.xeh[(size_t)b * 1024 + 512 + d] = (short)f2b(h2);
        int tok = p.target[b * T_ + step];
        p.xeh[(size_t)b * 1024 + d] = (short)f2b(p.E[(size_t)tok * D_ + d]);
    }
}

// ---------------- q GEMM 64x32 tiles -> bf16 q ----------------
__device__ __forceinline__ void q_phase(const P& p, OutS& sh, int bid)
{
    const int t = threadIdx.x, lane = t & 63, wave = t >> 6;
    const int lrow = lane & 15, kq = lane >> 4;
    const int srow = t >> 3, sseg = t & 7;
    const int m0 = (bid >> 4) * 64, n0 = (bid & 15) * 32;
    f32x4 acc0 = {}, acc1 = {};
    for (int k0 = 0; k0 < 512; k0 += 64) {
        s16x8 va0 = *(const s16x8*)(p.hcbf + (size_t)(m0 + srow) * 512 + k0 + sseg * 8);
        s16x8 va1 = *(const s16x8*)(p.hcbf + (size_t)(m0 + srow + 32) * 512 + k0 + sseg * 8);
        int brow = n0 + (srow & 31);
        s16x8 vb0 = *(const s16x8*)(p.WaT + (size_t)brow * 512 + k0 + sseg * 8);
        __syncthreads();
        *(s16x8*)(&sh.As[srow][sseg * 8]) = va0;
        *(s16x8*)(&sh.As[srow + 32][sseg * 8]) = va1;
        if (srow < 32) *(s16x8*)(&sh.Bs[srow][sseg * 8]) = vb0;
        __syncthreads();
        #pragma unroll
        for (int kk = 0; kk < 64; kk += 32) {
            s16x8 af  = *(const s16x8*)(&sh.As[wave * 16 + lrow][kk + kq * 8]);
            s16x8 bf0 = *(const s16x8*)(&sh.Bs[lrow][kk + kq * 8]);
            s16x8 bf1 = *(const s16x8*)(&sh.Bs[16 + lrow][kk + kq * 8]);
            acc0 = __builtin_amdgcn_mfma_f32_16x16x32_bf16(af, bf0, acc0, 0, 0, 0);
            acc1 = __builtin_amdgcn_mfma_f32_16x16x32_bf16(af, bf1, acc1, 0, 0, 0);
        }
    }
    #pragma unroll
    for (int n2 = 0; n2 < 2; ++n2) {
        int col = n0 + n2 * 16 + lrow;
        float bvv = p.ba[col];
        f32x4 av = n2 ? acc1 : acc0;
        #pragma unroll
        for (int j = 0; j < 4; ++j) {
            int row = m0 + wave * 16 + kq * 4 + j;
            p.qbf[(size_t)row * 512 + col] = (short)f2b(av[j] + bvv);
        }
    }
}

// ---------------- out GEMM (M=512,N=128,K=512) + fused log_softmax ----------------
__device__ __forceinline__ void out_phase(const P& p, OutS& sh, int obid, int step)
{
    const int t = threadIdx.x, lane = t & 63, wave = t >> 6;
    const int lrow = lane & 15, kq = lane >> 4;
    const int srow = t >> 3, sseg = t & 7;
    const int m0 = obid * 64;
    f32x4 acc[8] = {};
    for (int k0 = 0; k0 < 512; k0 += 64) {
        s16x8 va0 = *(const s16x8*)(p.h2bf + (size_t)(m0 + srow) * 512 + k0 + sseg * 8);
        s16x8 va1 = *(const s16x8*)(p.h2bf + (size_t)(m0 + srow + 32) * 512 + k0 + sseg * 8);
        s16x8 vb[4];
        #pragma unroll
        for (int p4 = 0; p4 < 4; ++p4)
            vb[p4] = *(const s16x8*)(p.WoutT + (size_t)(srow + p4 * 32) * 512 + k0 + sseg * 8);
        __syncthreads();
        *(s16x8*)(&sh.As[srow][sseg * 8]) = va0;
        *(s16x8*)(&sh.As[srow + 32][sseg * 8]) = va1;
        #pragma unroll
        for (int p4 = 0; p4 < 4; ++p4) *(s16x8*)(&sh.Bs[srow + p4 * 32][sseg * 8]) = vb[p4];
        __syncthreads();
        #pragma unroll
        for (int kk = 0; kk < 64; kk += 32) {
            s16x8 a = *(const s16x8*)(&sh.As[wave * 16 + lrow][kk + kq * 8]);
            #pragma unroll
            for (int f = 0; f < 8; ++f) {
                s16x8 b = *(const s16x8*)(&sh.Bs[f * 16 + lrow][kk + kq * 8]);
                acc[f] = __builtin_amdgcn_mfma_f32_16x16x32_bf16(a, b, acc[f], 0, 0, 0);
            }
        }
    }
    float colb[8];
    #pragma unroll
    for (int f = 0; f < 8; ++f) colb[f] = p.bout[f * 16 + lrow];
    #pragma unroll
    for (int j = 0; j < 4; ++j) {
        float v[8]; float mx = -1e30f;
        #pragma unroll
        for (int f = 0; f < 8; ++f) { v[f] = acc[f][j] + colb[f]; mx = fmaxf(mx, v[f]); }
        #pragma unroll
        for (int o = 1; o < 16; o <<= 1) mx = fmaxf(mx, __shfl_xor(mx, o));
        float sum = 0.f;
        #pragma unroll
        for (int f = 0; f < 8; ++f) sum += __expf(v[f] - mx);
        #pragma unroll
        for (int o = 1; o < 16; o <<= 1) sum += __shfl_xor(sum, o);
        float lse = mx + __logf(sum);
        int row = m0 + wave * 16 + kq * 4 + j;
        float* orow = p.out_logits + ((size_t)row * T_ + step) * V_;
        #pragma unroll
        for (int f = 0; f < 8; ++f) orow[f * 16 + lrow] = v[f] - lse;
    }
}

// ---------------- per-step dispatches ----------------
__global__ __launch_bounds__(256, 2) void kA(P p, int step) {
    __shared__ AttnS sh;
    attn_phase(p, sh, blockIdx.x, step);
}
__global__ __launch_bounds__(256, 2) void kB(P p, int step) {
    __shared__ GateS sh;
    fgate_phase(p, sh, blockIdx.x, step);
}
// C: q(0..127) | pgate(128..255) | out(256..263).  INIT skips out.
template<bool INIT>
__global__ __launch_bounds__(256, 2) void kC(P p, int step) {
    __shared__ SharedC sh;
    const int bid = blockIdx.x;
    if (bid < 128)       q_phase(p, sh.o, bid);
    else if (bid < 256)  pgate_phase(p, sh.g, bid - 128);
    else if (!INIT)      out_phase(p, sh.o, bid - 256, step);
}

// ---------------- precompute kernels ----------------
__global__ __launch_bounds__(256)
void gemm64(const short* __restrict__ A, const short* __restrict__ Bt,
            const float* __restrict__ bias, short* __restrict__ Cp,
            int M, int N, int K)
{
    __shared__ __align__(16) short As[64][LDW];
    __shared__ __align__(16) short Bs[64][LDW];
    const int t = threadIdx.x;
    const int lane = t & 63, wave = t >> 6;
    const int wr = wave >> 1, wc = wave & 1;
    const int lrow = lane & 15, kq = lane >> 4;
    const int m0 = blockIdx.y * 64, n0 = blockIdx.x * 64;
    const int srow = t >> 3, sseg = t & 7;
    f32x4 acc[2][2] = {};
    for (int k0 = 0; k0 < K; k0 += 64) {
        s16x8 va0 = *(const s16x8*)(A + (size_t)(m0 + srow) * K + k0 + sseg * 8);
        s16x8 va1 = *(const s16x8*)(A + (size_t)(m0 + srow + 32) * K + k0 + sseg * 8);
        s16x8 vb0 = *(const s16x8*)(Bt + (size_t)(n0 + srow) * K + k0 + sseg * 8);
        s16x8 vb1 = *(const s16x8*)(Bt + (size_t)(n0 + srow + 32) * K + k0 + sseg * 8);
        __syncthreads();
        *(s16x8*)(&As[srow][sseg * 8]) = va0;
        *(s16x8*)(&As[srow + 32][sseg * 8]) = va1;
        *(s16x8*)(&Bs[srow][sseg * 8]) = vb0;
        *(s16x8*)(&Bs[srow + 32][sseg * 8]) = vb1;
        __syncthreads();
        for (int kk = 0; kk < 64; kk += 32) {
            s16x8 af[2], bf[2];
            af[0] = *(const s16x8*)(&As[wr * 32 + lrow][kk + kq * 8]);
            af[1] = *(const s16x8*)(&As[wr * 32 + 16 + lrow][kk + kq * 8]);
            bf[0] = *(const s16x8*)(&Bs[wc * 32 + lrow][kk + kq * 8]);
            bf[1] = *(const s16x8*)(&Bs[wc * 32 + 16 + lrow][kk + kq * 8]);
            for (int m2 = 0; m2 < 2; ++m2)
                for (int n2 = 0; n2 < 2; ++n2)
                    acc[m2][n2] = __builtin_amdgcn_mfma_f32_16x16x32_bf16(af[m2], bf[n2], acc[m2][n2], 0, 0, 0);
        }
    }
    for (int m2 = 0; m2 < 2; ++m2)
        for (int n2 = 0; n2 < 2; ++n2) {
            int col = n0 + wc * 32 + n2 * 16 + lrow;
            float bvv = bias ? bias[col] : 0.0f;
            for (int j = 0; j < 4; ++j) {
                int row = m0 + wr * 32 + m2 * 16 + kq * 4 + j;
                Cp[(size_t)row * N + col] = (short)f2b(acc[m2][n2][j] + bvv);
            }
        }
}

__global__ __launch_bounds__(256)
void init_state(const float* __restrict__ e_h, const float* __restrict__ e_c,
                float* __restrict__ c, short* __restrict__ hcbf,
                short* __restrict__ xeh, const float* __restrict__ E)
{
    int gid = blockIdx.x * 256 + threadIdx.x;
    int b = gid >> 9, d = gid & 511;
    float h0 = e_h[gid], c0 = e_c[gid];
    c[gid] = c0;
    hcbf[gid] = (short)f2b(h0 + c0);
    xeh[(size_t)b * 1024 + 512 + d] = (short)f2b(h0);
    xeh[(size_t)b * 1024 + d] = (short)f2b(E[d]);   // token 0 (SOS)
}

__global__ __launch_bounds__(256)
void transpose_cast(const float* __restrict__ in, short* __restrict__ out,
                    int N, int ostride, int koff, int gate_perm)
{
    __shared__ float tile[64][65];
    int t = threadIdx.x;
    int n0 = blockIdx.x * 64, k0 = blockIdx.y * 64;
    int cc = t & 63, r4 = t >> 6;
    for (int i = 0; i < 16; ++i) {
        int r = i * 4 + r4;
        tile[r][cc] = in[(size_t)(k0 + r) * N + n0 + cc];
    }
    __syncthreads();
    for (int i = 0; i < 16; ++i) {
        int nr = i * 4 + r4;
        int ng = n0 + nr;
        int np = gate_perm ? ((ng & 511) * 4 + (ng >> 9)) : ng;
        out[(size_t)np * ostride + koff + k0 + cc] = (short)f2b(tile[cc][nr]);
    }
}

__global__ __launch_bounds__(256)
void cast_bf16_v4(const float* __restrict__ in, short* __restrict__ out, int n4)
{
    int i = blockIdx.x * 256 + threadIdx.x;
    int stride = gridDim.x * 256;
    for (; i < n4; i += stride) {
        f32x4 v = ((const f32x4*)in)[i];
        s16x4 o;
        for (int j = 0; j < 4; ++j) o[j] = (short)f2b(v[j]);
        ((s16x4*)out)[i] = o;
    }
}

__global__ __launch_bounds__(256)
void make_bcat(const float* __restrict__ b_ih, const float* __restrict__ b_hh, float* __restrict__ bcat)
{
    int i = blockIdx.x * 256 + threadIdx.x;
    if (i < 2048) {
        int np = (i & 511) * 4 + (i >> 9);
        bcat[np] = b_ih[i] + b_hh[i];
    }
}

extern "C" void kernel_launch(void* const* d_in, const int* in_sizes, int n_in,
                              void* d_out, int out_size, void* d_ws, size_t ws_size,
                              hipStream_t stream)
{
    const float* e_all  = (const float*)d_in[0];
    const float* e_h    = (const float*)d_in[1];
    const float* e_c    = (const float*)d_in[2];
    const int*   target = (const int*)d_in[3];
    const float* E      = (const float*)d_in[4];
    const float* Wa     = (const float*)d_in[5];
    const float* ba     = (const float*)d_in[6];
    const float* Ua     = (const float*)d_in[7];
    const float* bu     = (const float*)d_in[8];
    const float* Va     = (const float*)d_in[9];
    const float* bv     = (const float*)d_in[10];
    const float* W_ih   = (const float*)d_in[11];
    const float* b_ih   = (const float*)d_in[12];
    const float* W_hh   = (const float*)d_in[13];
    const float* b_hh   = (const float*)d_in[14];
    const float* W_out  = (const float*)d_in[15];
    const float* b_out  = (const float*)d_in[16];

    char* ws = (char*)d_ws;
    size_t off = 0;
    auto alloc = [&](size_t bytes) { void* p = ws + off; off += (bytes + 255) & ~255ull; return p; };
    short* ealb  = (short*)alloc((size_t)B_ * S_ * D_ * 2);
    short* kpb   = (short*)alloc((size_t)B_ * S_ * D_ * 2);
    short* WaT   = (short*)alloc((size_t)D_ * D_ * 2);
    short* UaT   = (short*)alloc((size_t)D_ * D_ * 2);
    short* WehT  = (short*)alloc((size_t)2048 * 1024 * 2);
    short* WctxT = (short*)alloc((size_t)2048 * 512 * 2);
    short* WoutT = (short*)alloc((size_t)V_ * D_ * 2);
    float* bcat  = (float*)alloc(2048 * 4);
    short* qbf   = (short*)alloc((size_t)B_ * D_ * 2);
    short* vab   = (short*)alloc((size_t)D_ * 2);
    short* xeh   = (short*)alloc((size_t)B_ * 1024 * 2);
    short* ctxb  = (short*)alloc((size_t)B_ * D_ * 2);
    float* gp    = (float*)alloc((size_t)B_ * 2048 * 4);
    short* hcbf  = (short*)alloc((size_t)B_ * D_ * 2);
    short* h2bf  = (short*)alloc((size_t)B_ * D_ * 2);
    float* cst   = (float*)alloc((size_t)B_ * D_ * 4);
    if (off > ws_size) return;

    float* out_logits = (float*)d_out;                        // [B,T,V]
    float* out_attn   = (float*)d_out + (size_t)B_ * T_ * V_; // [B,T,S]

    // ---- precompute ----
    cast_bf16_v4<<<4096, 256, 0, stream>>>(e_all, ealb, B_ * S_ * D_ / 4);
    cast_bf16_v4<<<1,    256, 0, stream>>>(Va, vab, D_ / 4);
    transpose_cast<<<dim3(8, 8),  256, 0, stream>>>(Wa,  WaT,  512,  512, 0, 0);
    transpose_cast<<<dim3(8, 8),  256, 0, stream>>>(Ua,  UaT,  512,  512, 0, 0);
    transpose_cast<<<dim3(32, 8), 256, 0, stream>>>(W_ih,              WehT,  2048, 1024, 0,   1);
    transpose_cast<<<dim3(32, 8), 256, 0, stream>>>(W_ih + 512 * 2048, WctxT, 2048, 512,  0,   1);
    transpose_cast<<<dim3(32, 8), 256, 0, stream>>>(W_hh,              WehT,  2048, 1024, 512, 1);
    transpose_cast<<<dim3(2, 8),  256, 0, stream>>>(W_out, WoutT, 128, 512, 0, 0);
    make_bcat<<<8, 256, 0, stream>>>(b_ih, b_hh, bcat);
    gemm64<<<dim3(8, 1024), 256, 0, stream>>>(ealb, UaT, bu, kpb, B_ * S_, 512, 512);
    init_state<<<1024, 256, 0, stream>>>(e_h, e_c, cst, hcbf, xeh, E);

    P pp;
    pp.target = target; pp.E = E; pp.bv = bv; pp.ba = ba; pp.bout = b_out;
    pp.vab = vab;
    pp.ealb = ealb; pp.kpb = kpb; pp.WaT = WaT; pp.WehT = WehT; pp.WctxT = WctxT; pp.WoutT = WoutT;
    pp.bcat = bcat; pp.qbf = qbf; pp.xeh = xeh; pp.ctxb = ctxb; pp.gp = gp;
    pp.hcbf = hcbf; pp.h2bf = h2bf; pp.cst = cst;
    pp.out_logits = out_logits; pp.out_attn = out_attn;

    // q(0) + pgate(0) from initial state
    kC<true><<<256, 256, 0, stream>>>(pp, 0);

    // ---- sequential decode: A(attn) -> B(fgate+LSTM) -> C(q ∥ pgate ∥ out) ----
    for (int t = 0; t < T_; ++t) {
        kA<<<512, 256, 0, stream>>>(pp, t);
        kB<<<256, 256, 0, stream>>>(pp, t);
        kC<false><<<264, 256, 0, stream>>>(pp, t);
    }
    (void)n_in; (void)in_sizes; (void)out_size;
}

// Round 7
// 6507.194 us; speedup vs baseline: 1.1436x; 1.0190x over previous
//
#include <hip/hip_runtime.h>

#define B_ 512
#define S_ 128
#define T_ 128
#define D_ 512
#define V_ 128
#define LDW 72   // 144B row stride -> 2-way LDS bank aliasing on ds_read_b128 (free)

typedef __attribute__((ext_vector_type(8))) short s16x8;
typedef __attribute__((ext_vector_type(4))) short s16x4;
typedef __attribute__((ext_vector_type(4))) float f32x4;

__device__ __forceinline__ float b2f(unsigned short h) {
    union { unsigned int u; float f; } x; x.u = ((unsigned int)h) << 16; return x.f;
}
__device__ __forceinline__ unsigned short f2b(float f) {
    union { float f; unsigned int u; } x; x.f = f;
    unsigned int u = x.u; u += 0x7FFFu + ((u >> 16) & 1u);
    return (unsigned short)(u >> 16);
}
#if __has_builtin(__builtin_amdgcn_rcpf)
__device__ __forceinline__ float rcp_f(float x) { return __builtin_amdgcn_rcpf(x); }
#else
__device__ __forceinline__ float rcp_f(float x) { return 1.0f / x; }
#endif
__device__ __forceinline__ float sigm(float x) { return rcp_f(1.0f + __expf(-x)); }
__device__ __forceinline__ float tanh_fast(float x) {
    float e = __expf(2.0f * fabsf(x));          // e^{2|x|}; inf -> rcp=0 -> 1.0
    float r = 1.0f - 2.0f * rcp_f(e + 1.0f);
    return copysignf(r, x);
}

struct P {
    const int* target;
    const float* E; const float* bv; const float* ba; const float* bout;
    const short* vab;
    const short* ealb; const short* kpT;
    const short* WaT; const short* WehT; const short* WctxT; const short* WoutT;
    const float* bcat;
    short* qbf; short* xeh; short* ctxb; short* gpb;
    short* hcbf; short* h2bf; float* cst;
    float* out_logits; float* out_attn;
};

struct AttnS { float scp[4][64]; float wbuf[S_]; float cpart[4][D_]; };
struct OutS  { short As[64][LDW]; short Bs[128][LDW]; };
struct PG2   { short As[128][LDW]; short Bs[64][LDW]; };
struct GateS { short As[64][LDW]; short Bs[64][LDW]; float gt[64][65]; };
union SharedA { AttnS a; OutS o; };
union SharedC { OutS o; PG2 g; };

// ---------------- attention: lane-per-s coalesced scores + wave0 softmax + ctx ----------------
// kpT layout: [b][g=d/8][s][8]  -> lane l (s=l) reads 16B at g*1024+s*8; 64 lanes = 1KB contiguous
__device__ __forceinline__ void attn_phase(const P& p, AttnS& sh, int b, int step)
{
    const int t = threadIdx.x, lane = t & 63, wave = t >> 6;
    {
        const int sg = wave & 1, dh = wave >> 1;     // s-group, d-half
        const int s = sg * 64 + lane;
        const short* kb = p.kpT + (size_t)b * (64 * 1024);
        const short* qv = p.qbf + (size_t)b * D_;
        float acc = 0.f;
        #pragma unroll 4
        for (int i = 0; i < 32; ++i) {
            int g = dh * 32 + i;
            s16x8 kv = *(const s16x8*)(kb + g * 1024 + s * 8);
            s16x8 qk = *(const s16x8*)(qv + g * 8);        // wave-uniform
            s16x8 vk = *(const s16x8*)(p.vab + g * 8);     // wave-uniform
            #pragma unroll
            for (int j = 0; j < 8; ++j)
                acc += tanh_fast(b2f((unsigned short)qk[j]) + b2f((unsigned short)kv[j]))
                       * b2f((unsigned short)vk[j]);
        }
        sh.scp[wave][lane] = acc;
    }
    __syncthreads();
    if (wave == 0) {
        const float bvv = p.bv[0];
        float v0 = sh.scp[0][lane] + sh.scp[2][lane] + bvv;   // s = lane
        float v1 = sh.scp[1][lane] + sh.scp[3][lane] + bvv;   // s = lane + 64
        float m = fmaxf(v0, v1);
        #pragma unroll
        for (int o = 32; o >= 1; o >>= 1) m = fmaxf(m, __shfl_xor(m, o));
        float e0 = __expf(v0 - m), e1 = __expf(v1 - m);
        float su = e0 + e1;
        #pragma unroll
        for (int o = 32; o >= 1; o >>= 1) su += __shfl_xor(su, o);
        float inv = rcp_f(su);
        float w0 = e0 * inv, w1 = e1 * inv;
        sh.wbuf[lane] = w0; sh.wbuf[lane + 64] = w1;
        float* ao = p.out_attn + ((size_t)b * T_ + step) * S_;
        ao[lane] = w0; ao[lane + 64] = w1;
    }
    __syncthreads();
    {
        const int d0 = lane * 8;
        f32x4 aA = {0.f,0.f,0.f,0.f}, aB = {0.f,0.f,0.f,0.f};
        const short* eb = p.ealb + (size_t)b * S_ * D_ + d0;
        #pragma unroll 4
        for (int i = 0; i < 32; ++i) {
            int s = wave * 32 + i;
            float wv = sh.wbuf[s];
            s16x8 ev = *(const s16x8*)(eb + (size_t)s * D_);
            #pragma unroll
            for (int j = 0; j < 4; ++j) aA[j] += wv * b2f((unsigned short)ev[j]);
            #pragma unroll
            for (int j = 0; j < 4; ++j) aB[j] += wv * b2f((unsigned short)ev[4 + j]);
        }
        *(f32x4*)&sh.cpart[wave][d0]     = aA;
        *(f32x4*)&sh.cpart[wave][d0 + 4] = aB;
    }
    __syncthreads();
    {
        int dd = t * 2;
        float v0 = sh.cpart[0][dd]   + sh.cpart[1][dd]   + sh.cpart[2][dd]   + sh.cpart[3][dd];
        float v1 = sh.cpart[0][dd+1] + sh.cpart[1][dd+1] + sh.cpart[2][dd+1] + sh.cpart[3][dd+1];
        short2 o2; o2.x = (short)f2b(v0); o2.y = (short)f2b(v1);
        *(short2*)(p.ctxb + (size_t)b * D_ + dd) = o2;
    }
}

// ---------------- partial gate GEMM 128x64: Gp = [emb,h] @ W_eh^T + bcat (K=1024) -> bf16 ----------
__device__ __forceinline__ void pgate_phase(const P& p, PG2& sh, int bid2)
{
    const int t = threadIdx.x, lane = t & 63, wave = t >> 6;
    const int lrow = lane & 15, kq = lane >> 4;
    const int m0 = (bid2 >> 5) * 128, n0 = (bid2 & 31) * 64;
    const int K = 1024;
    f32x4 acc[2][4] = {};
    for (int k0 = 0; k0 < K; k0 += 64) {
        s16x8 va[4], vb[2];
        #pragma unroll
        for (int r = 0; r < 4; ++r) {
            int idx = r * 256 + t, row = idx >> 3, seg = idx & 7;
            va[r] = *(const s16x8*)(p.xeh + (size_t)(m0 + row) * K + k0 + seg * 8);
        }
        #pragma unroll
        for (int r = 0; r < 2; ++r) {
            int idx = r * 256 + t, row = idx >> 3, seg = idx & 7;
            vb[r] = *(const s16x8*)(p.WehT + (size_t)(n0 + row) * K + k0 + seg * 8);
        }
        __syncthreads();
        #pragma unroll
        for (int r = 0; r < 4; ++r) {
            int idx = r * 256 + t, row = idx >> 3, seg = idx & 7;
            *(s16x8*)(&sh.As[row][seg * 8]) = va[r];
        }
        #pragma unroll
        for (int r = 0; r < 2; ++r) {
            int idx = r * 256 + t, row = idx >> 3, seg = idx & 7;
            *(s16x8*)(&sh.Bs[row][seg * 8]) = vb[r];
        }
        __syncthreads();
        #pragma unroll
        for (int kk = 0; kk < 64; kk += 32) {
            s16x8 af[2], bf[4];
            af[0] = *(const s16x8*)(&sh.As[wave * 32 + lrow][kk + kq * 8]);
            af[1] = *(const s16x8*)(&sh.As[wave * 32 + 16 + lrow][kk + kq * 8]);
            #pragma unroll
            for (int f = 0; f < 4; ++f)
                bf[f] = *(const s16x8*)(&sh.Bs[f * 16 + lrow][kk + kq * 8]);
            #pragma unroll
            for (int m2 = 0; m2 < 2; ++m2)
                #pragma unroll
                for (int n2 = 0; n2 < 4; ++n2)
                    acc[m2][n2] = __builtin_amdgcn_mfma_f32_16x16x32_bf16(af[m2], bf[n2], acc[m2][n2], 0, 0, 0);
        }
    }
    #pragma unroll
    for (int m2 = 0; m2 < 2; ++m2)
        #pragma unroll
        for (int n2 = 0; n2 < 4; ++n2) {
            int col = n0 + n2 * 16 + lrow;
            float bvv = p.bcat[col];
            #pragma unroll
            for (int j = 0; j < 4; ++j) {
                int row = m0 + wave * 32 + m2 * 16 + kq * 4 + j;
                p.gpb[(size_t)row * 2048 + col] = (short)f2b(acc[m2][n2][j] + bvv);
            }
        }
}

// ---------------- final gate GEMM (K=512, ctx) + Gp + fused LSTM ----------------
__device__ __forceinline__ void fgate_phase(const P& p, GateS& sh, int bid, int step)
{
    const int t = threadIdx.x, lane = t & 63, wave = t >> 6;
    const int wr = wave >> 1, wc = wave & 1;
    const int lrow = lane & 15, kq = lane >> 4;
    const int srow = t >> 3, sseg = t & 7;
    const int m0 = (bid >> 5) * 64, n0 = (bid & 31) * 64;
    f32x4 acc[2][2] = {};
    for (int k0 = 0; k0 < 512; k0 += 64) {
        s16x8 va0 = *(const s16x8*)(p.ctxb + (size_t)(m0 + srow) * 512 + k0 + sseg * 8);
        s16x8 va1 = *(const s16x8*)(p.ctxb + (size_t)(m0 + srow + 32) * 512 + k0 + sseg * 8);
        s16x8 vb0 = *(const s16x8*)(p.WctxT + (size_t)(n0 + srow) * 512 + k0 + sseg * 8);
        s16x8 vb1 = *(const s16x8*)(p.WctxT + (size_t)(n0 + srow + 32) * 512 + k0 + sseg * 8);
        __syncthreads();
        *(s16x8*)(&sh.As[srow][sseg * 8]) = va0;
        *(s16x8*)(&sh.As[srow + 32][sseg * 8]) = va1;
        *(s16x8*)(&sh.Bs[srow][sseg * 8]) = vb0;
        *(s16x8*)(&sh.Bs[srow + 32][sseg * 8]) = vb1;
        __syncthreads();
        #pragma unroll
        for (int kk = 0; kk < 64; kk += 32) {
            s16x8 af0 = *(const s16x8*)(&sh.As[wr * 32 + lrow][kk + kq * 8]);
            s16x8 af1 = *(const s16x8*)(&sh.As[wr * 32 + 16 + lrow][kk + kq * 8]);
            s16x8 bf0 = *(const s16x8*)(&sh.Bs[wc * 32 + lrow][kk + kq * 8]);
            s16x8 bf1 = *(const s16x8*)(&sh.Bs[wc * 32 + 16 + lrow][kk + kq * 8]);
            acc[0][0] = __builtin_amdgcn_mfma_f32_16x16x32_bf16(af0, bf0, acc[0][0], 0, 0, 0);
            acc[0][1] = __builtin_amdgcn_mfma_f32_16x16x32_bf16(af0, bf1, acc[0][1], 0, 0, 0);
            acc[1][0] = __builtin_amdgcn_mfma_f32_16x16x32_bf16(af1, bf0, acc[1][0], 0, 0, 0);
            acc[1][1] = __builtin_amdgcn_mfma_f32_16x16x32_bf16(af1, bf1, acc[1][1], 0, 0, 0);
        }
    }
    #pragma unroll
    for (int m2 = 0; m2 < 2; ++m2)
        #pragma unroll
        for (int n2 = 0; n2 < 2; ++n2) {
            int cl = wc * 32 + n2 * 16 + lrow;
            #pragma unroll
            for (int j = 0; j < 4; ++j) {
                int rl = wr * 32 + m2 * 16 + kq * 4 + j;
                sh.gt[rl][cl] = acc[m2][n2][j]
                              + b2f((unsigned short)p.gpb[(size_t)(m0 + rl) * 2048 + n0 + cl]);
            }
        }
    __syncthreads();
    const int rl4 = t >> 4, dl = t & 15;
    #pragma unroll
    for (int pass = 0; pass < 4; ++pass) {
        int row = pass * 16 + rl4;
        int b = m0 + row;
        int d = (n0 >> 2) + dl;
        float gi = sh.gt[row][dl * 4 + 0];
        float gf = sh.gt[row][dl * 4 + 1];
        float gg = sh.gt[row][dl * 4 + 2];
        float go = sh.gt[row][dl * 4 + 3];
        float cv = p.cst[(size_t)b * D_ + d];
        float c2 = sigm(gf) * cv + sigm(gi) * tanh_fast(gg);
        float h2 = sigm(go) * tanh_fast(c2);
        p.cst[(size_t)b * D_ + d] = c2;
        p.hcbf[(size_t)b * D_ + d] = (short)f2b(h2 + c2);
        p.h2bf[(size_t)b * D_ + d] = (short)f2b(h2);
        p.xeh[(size_t)b * 1024 + 512 + d] = (short)f2b(h2);
        int tok = p.target[b * T_ + step];
        p.xeh[(size_t)b * 1024 + d] = (short)f2b(p.E[(size_t)tok * D_ + d]);
    }
}

// ---------------- q GEMM 64x32 tiles -> bf16 q ----------------
__device__ __forceinline__ void q_phase(const P& p, OutS& sh, int bid)
{
    const int t = threadIdx.x, lane = t & 63, wave = t >> 6;
    const int lrow = lane & 15, kq = lane >> 4;
    const int srow = t >> 3, sseg = t & 7;
    const int m0 = (bid >> 4) * 64, n0 = (bid & 15) * 32;
    f32x4 acc0 = {}, acc1 = {};
    for (int k0 = 0; k0 < 512; k0 += 64) {
        s16x8 va0 = *(const s16x8*)(p.hcbf + (size_t)(m0 + srow) * 512 + k0 + sseg * 8);
        s16x8 va1 = *(const s16x8*)(p.hcbf + (size_t)(m0 + srow + 32) * 512 + k0 + sseg * 8);
        int brow = n0 + (srow & 31);
        s16x8 vb0 = *(const s16x8*)(p.WaT + (size_t)brow * 512 + k0 + sseg * 8);
        __syncthreads();
        *(s16x8*)(&sh.As[srow][sseg * 8]) = va0;
        *(s16x8*)(&sh.As[srow + 32][sseg * 8]) = va1;
        if (srow < 32) *(s16x8*)(&sh.Bs[srow][sseg * 8]) = vb0;
        __syncthreads();
        #pragma unroll
        for (int kk = 0; kk < 64; kk += 32) {
            s16x8 af  = *(const s16x8*)(&sh.As[wave * 16 + lrow][kk + kq * 8]);
            s16x8 bf0 = *(const s16x8*)(&sh.Bs[lrow][kk + kq * 8]);
            s16x8 bf1 = *(const s16x8*)(&sh.Bs[16 + lrow][kk + kq * 8]);
            acc0 = __builtin_amdgcn_mfma_f32_16x16x32_bf16(af, bf0, acc0, 0, 0, 0);
            acc1 = __builtin_amdgcn_mfma_f32_16x16x32_bf16(af, bf1, acc1, 0, 0, 0);
        }
    }
    #pragma unroll
    for (int n2 = 0; n2 < 2; ++n2) {
        int col = n0 + n2 * 16 + lrow;
        float bvv = p.ba[col];
        f32x4 av = n2 ? acc1 : acc0;
        #pragma unroll
        for (int j = 0; j < 4; ++j) {
            int row = m0 + wave * 16 + kq * 4 + j;
            p.qbf[(size_t)row * 512 + col] = (short)f2b(av[j] + bvv);
        }
    }
}

// ---------------- out GEMM (M=512,N=128,K=512) + fused log_softmax ----------------
__device__ __forceinline__ void out_phase(const P& p, OutS& sh, int obid, int step)
{
    const int t = threadIdx.x, lane = t & 63, wave = t >> 6;
    const int lrow = lane & 15, kq = lane >> 4;
    const int srow = t >> 3, sseg = t & 7;
    const int m0 = obid * 64;
    f32x4 acc[8] = {};
    for (int k0 = 0; k0 < 512; k0 += 64) {
        s16x8 va0 = *(const s16x8*)(p.h2bf + (size_t)(m0 + srow) * 512 + k0 + sseg * 8);
        s16x8 va1 = *(const s16x8*)(p.h2bf + (size_t)(m0 + srow + 32) * 512 + k0 + sseg * 8);
        s16x8 vb[4];
        #pragma unroll
        for (int p4 = 0; p4 < 4; ++p4)
            vb[p4] = *(const s16x8*)(p.WoutT + (size_t)(srow + p4 * 32) * 512 + k0 + sseg * 8);
        __syncthreads();
        *(s16x8*)(&sh.As[srow][sseg * 8]) = va0;
        *(s16x8*)(&sh.As[srow + 32][sseg * 8]) = va1;
        #pragma unroll
        for (int p4 = 0; p4 < 4; ++p4) *(s16x8*)(&sh.Bs[srow + p4 * 32][sseg * 8]) = vb[p4];
        __syncthreads();
        #pragma unroll
        for (int kk = 0; kk < 64; kk += 32) {
            s16x8 a = *(const s16x8*)(&sh.As[wave * 16 + lrow][kk + kq * 8]);
            #pragma unroll
            for (int f = 0; f < 8; ++f) {
                s16x8 b = *(const s16x8*)(&sh.Bs[f * 16 + lrow][kk + kq * 8]);
                acc[f] = __builtin_amdgcn_mfma_f32_16x16x32_bf16(a, b, acc[f], 0, 0, 0);
            }
        }
    }
    float colb[8];
    #pragma unroll
    for (int f = 0; f < 8; ++f) colb[f] = p.bout[f * 16 + lrow];
    #pragma unroll
    for (int j = 0; j < 4; ++j) {
        float v[8]; float mx = -1e30f;
        #pragma unroll
        for (int f = 0; f < 8; ++f) { v[f] = acc[f][j] + colb[f]; mx = fmaxf(mx, v[f]); }
        #pragma unroll
        for (int o = 1; o < 16; o <<= 1) mx = fmaxf(mx, __shfl_xor(mx, o));
        float sum = 0.f;
        #pragma unroll
        for (int f = 0; f < 8; ++f) sum += __expf(v[f] - mx);
        #pragma unroll
        for (int o = 1; o < 16; o <<= 1) sum += __shfl_xor(sum, o);
        float lse = mx + __logf(sum);
        int row = m0 + wave * 16 + kq * 4 + j;
        float* orow = p.out_logits + ((size_t)row * T_ + step) * V_;
        #pragma unroll
        for (int f = 0; f < 8; ++f) orow[f * 16 + lrow] = v[f] - lse;
    }
}

// ---------------- per-step dispatches ----------------
// A: attn(0..511) | out_{t-1}(512..519, skipped at t=0)
__global__ __launch_bounds__(256, 2) void kA(P p, int step) {
    __shared__ SharedA sh;
    const int bid = blockIdx.x;
    if (bid < 512)     attn_phase(p, sh.a, bid, step);
    else if (step > 0) out_phase(p, sh.o, bid - 512, step - 1);
}
__global__ __launch_bounds__(256, 2) void kB(P p, int step) {
    __shared__ GateS sh;
    fgate_phase(p, sh, blockIdx.x, step);
}
// C: q(0..127) | pgate(128..255)
__global__ __launch_bounds__(256, 2) void kC(P p) {
    __shared__ SharedC sh;
    const int bid = blockIdx.x;
    if (bid < 128) q_phase(p, sh.o, bid);
    else           pgate_phase(p, sh.g, bid - 128);
}
__global__ __launch_bounds__(256, 2) void kOutLast(P p, int step) {
    __shared__ OutS sh;
    out_phase(p, sh, blockIdx.x, step);
}

// ---------------- precompute kernels ----------------
__global__ __launch_bounds__(256)
void gemm64(const short* __restrict__ A, const short* __restrict__ Bt,
            const float* __restrict__ bias, short* __restrict__ Cp,
            int M, int N, int K)
{
    __shared__ __align__(16) short As[64][LDW];
    __shared__ __align__(16) short Bs[64][LDW];
    const int t = threadIdx.x;
    const int lane = t & 63, wave = t >> 6;
    const int wr = wave >> 1, wc = wave & 1;
    const int lrow = lane & 15, kq = lane >> 4;
    const int m0 = blockIdx.y * 64, n0 = blockIdx.x * 64;
    const int srow = t >> 3, sseg = t & 7;
    f32x4 acc[2][2] = {};
    for (int k0 = 0; k0 < K; k0 += 64) {
        s16x8 va0 = *(const s16x8*)(A + (size_t)(m0 + srow) * K + k0 + sseg * 8);
        s16x8 va1 = *(const s16x8*)(A + (size_t)(m0 + srow + 32) * K + k0 + sseg * 8);
        s16x8 vb0 = *(const s16x8*)(Bt + (size_t)(n0 + srow) * K + k0 + sseg * 8);
        s16x8 vb1 = *(const s16x8*)(Bt + (size_t)(n0 + srow + 32) * K + k0 + sseg * 8);
        __syncthreads();
        *(s16x8*)(&As[srow][sseg * 8]) = va0;
        *(s16x8*)(&As[srow + 32][sseg * 8]) = va1;
        *(s16x8*)(&Bs[srow][sseg * 8]) = vb0;
        *(s16x8*)(&Bs[srow + 32][sseg * 8]) = vb1;
        __syncthreads();
        for (int kk = 0; kk < 64; kk += 32) {
            s16x8 af[2], bf[2];
            af[0] = *(const s16x8*)(&As[wr * 32 + lrow][kk + kq * 8]);
            af[1] = *(const s16x8*)(&As[wr * 32 + 16 + lrow][kk + kq * 8]);
            bf[0] = *(const s16x8*)(&Bs[wc * 32 + lrow][kk + kq * 8]);
            bf[1] = *(const s16x8*)(&Bs[wc * 32 + 16 + lrow][kk + kq * 8]);
            for (int m2 = 0; m2 < 2; ++m2)
                for (int n2 = 0; n2 < 2; ++n2)
                    acc[m2][n2] = __builtin_amdgcn_mfma_f32_16x16x32_bf16(af[m2], bf[n2], acc[m2][n2], 0, 0, 0);
        }
    }
    for (int m2 = 0; m2 < 2; ++m2)
        for (int n2 = 0; n2 < 2; ++n2) {
            int col = n0 + wc * 32 + n2 * 16 + lrow;
            float bvv = bias ? bias[col] : 0.0f;
            for (int j = 0; j < 4; ++j) {
                int row = m0 + wr * 32 + m2 * 16 + kq * 4 + j;
                Cp[(size_t)row * N + col] = (short)f2b(acc[m2][n2][j] + bvv);
            }
        }
}

// kpb[b][s][d] -> kpT[b][d/8][s][8]
__global__ __launch_bounds__(256)
void transpose_kp(const short* __restrict__ in, short* __restrict__ out)
{
    const int b = blockIdx.x, t = threadIdx.x;
    const size_t base = (size_t)b * (S_ * D_);
    for (int k = t; k < 64 * S_; k += 256) {
        int g = k >> 7, s = k & 127;
        s16x8 v = *(const s16x8*)(in + base + (size_t)s * D_ + g * 8);
        *(s16x8*)(out + base + (size_t)g * (S_ * 8) + s * 8) = v;
    }
}

__global__ __launch_bounds__(256)
void init_state(const float* __restrict__ e_h, const float* __restrict__ e_c,
                float* __restrict__ c, short* __restrict__ hcbf,
                short* __restrict__ xeh, const float* __restrict__ E)
{
    int gid = blockIdx.x * 256 + threadIdx.x;
    int b = gid >> 9, d = gid & 511;
    float h0 = e_h[gid], c0 = e_c[gid];
    c[gid] = c0;
    hcbf[gid] = (short)f2b(h0 + c0);
    xeh[(size_t)b * 1024 + 512 + d] = (short)f2b(h0);
    xeh[(size_t)b * 1024 + d] = (short)f2b(E[d]);   // token 0 (SOS)
}

__global__ __launch_bounds__(256)
void transpose_cast(const float* __restrict__ in, short* __restrict__ out,
                    int N, int ostride, int koff, int gate_perm)
{
    __shared__ float tile[64][65];
    int t = threadIdx.x;
    int n0 = blockIdx.x * 64, k0 = blockIdx.y * 64;
    int cc = t & 63, r4 = t >> 6;
    for (int i = 0; i < 16; ++i) {
        int r = i * 4 + r4;
        tile[r][cc] = in[(size_t)(k0 + r) * N + n0 + cc];
    }
    __syncthreads();
    for (int i = 0; i < 16; ++i) {
        int nr = i * 4 + r4;
        int ng = n0 + nr;
        int np = gate_perm ? ((ng & 511) * 4 + (ng >> 9)) : ng;
        out[(size_t)np * ostride + koff + k0 + cc] = (short)f2b(tile[cc][nr]);
    }
}

__global__ __launch_bounds__(256)
void cast_bf16_v4(const float* __restrict__ in, short* __restrict__ out, int n4)
{
    int i = blockIdx.x * 256 + threadIdx.x;
    int stride = gridDim.x * 256;
    for (; i < n4; i += stride) {
        f32x4 v = ((const f32x4*)in)[i];
        s16x4 o;
        for (int j = 0; j < 4; ++j) o[j] = (short)f2b(v[j]);
        ((s16x4*)out)[i] = o;
    }
}

__global__ __launch_bounds__(256)
void make_bcat(const float* __restrict__ b_ih, const float* __restrict__ b_hh, float* __restrict__ bcat)
{
    int i = blockIdx.x * 256 + threadIdx.x;
    if (i < 2048) {
        int np = (i & 511) * 4 + (i >> 9);
        bcat[np] = b_ih[i] + b_hh[i];
    }
}

extern "C" void kernel_launch(void* const* d_in, const int* in_sizes, int n_in,
                              void* d_out, int out_size, void* d_ws, size_t ws_size,
                              hipStream_t stream)
{
    const float* e_all  = (const float*)d_in[0];
    const float* e_h    = (const float*)d_in[1];
    const float* e_c    = (const float*)d_in[2];
    const int*   target = (const int*)d_in[3];
    const float* E      = (const float*)d_in[4];
    const float* Wa     = (const float*)d_in[5];
    const float* ba     = (const float*)d_in[6];
    const float* Ua     = (const float*)d_in[7];
    const float* bu     = (const float*)d_in[8];
    const float* Va     = (const float*)d_in[9];
    const float* bv     = (const float*)d_in[10];
    const float* W_ih   = (const float*)d_in[11];
    const float* b_ih   = (const float*)d_in[12];
    const float* W_hh   = (const float*)d_in[13];
    const float* b_hh   = (const float*)d_in[14];
    const float* W_out  = (const float*)d_in[15];
    const float* b_out  = (const float*)d_in[16];

    char* ws = (char*)d_ws;
    size_t off = 0;
    auto alloc = [&](size_t bytes) { void* p = ws + off; off += (bytes + 255) & ~255ull; return p; };
    short* ealb  = (short*)alloc((size_t)B_ * S_ * D_ * 2);
    short* kpb   = (short*)alloc((size_t)B_ * S_ * D_ * 2);   // scratch (pre-transpose)
    short* kpT   = (short*)alloc((size_t)B_ * S_ * D_ * 2);   // [b][d/8][s][8]
    short* WaT   = (short*)alloc((size_t)D_ * D_ * 2);
    short* UaT   = (short*)alloc((size_t)D_ * D_ * 2);
    short* WehT  = (short*)alloc((size_t)2048 * 1024 * 2);
    short* WctxT = (short*)alloc((size_t)2048 * 512 * 2);
    short* WoutT = (short*)alloc((size_t)V_ * D_ * 2);
    float* bcat  = (float*)alloc(2048 * 4);
    short* qbf   = (short*)alloc((size_t)B_ * D_ * 2);
    short* vab   = (short*)alloc((size_t)D_ * 2);
    short* xeh   = (short*)alloc((size_t)B_ * 1024 * 2);
    short* ctxb  = (short*)alloc((size_t)B_ * D_ * 2);
    short* gpb   = (short*)alloc((size_t)B_ * 2048 * 2);
    short* hcbf  = (short*)alloc((size_t)B_ * D_ * 2);
    short* h2bf  = (short*)alloc((size_t)B_ * D_ * 2);
    float* cst   = (float*)alloc((size_t)B_ * D_ * 4);
    if (off > ws_size) return;

    float* out_logits = (float*)d_out;                        // [B,T,V]
    float* out_attn   = (float*)d_out + (size_t)B_ * T_ * V_; // [B,T,S]

    // ---- precompute ----
    cast_bf16_v4<<<4096, 256, 0, stream>>>(e_all, ealb, B_ * S_ * D_ / 4);
    cast_bf16_v4<<<1,    256, 0, stream>>>(Va, vab, D_ / 4);
    transpose_cast<<<dim3(8, 8),  256, 0, stream>>>(Wa,  WaT,  512,  512, 0, 0);
    transpose_cast<<<dim3(8, 8),  256, 0, stream>>>(Ua,  UaT,  512,  512, 0, 0);
    transpose_cast<<<dim3(32, 8), 256, 0, stream>>>(W_ih,              WehT,  2048, 1024, 0,   1);
    transpose_cast<<<dim3(32, 8), 256, 0, stream>>>(W_ih + 512 * 2048, WctxT, 2048, 512,  0,   1);
    transpose_cast<<<dim3(32, 8), 256, 0, stream>>>(W_hh,              WehT,  2048, 1024, 512, 1);
    transpose_cast<<<dim3(2, 8),  256, 0, stream>>>(W_out, WoutT, 128, 512, 0, 0);
    make_bcat<<<8, 256, 0, stream>>>(b_ih, b_hh, bcat);
    gemm64<<<dim3(8, 1024), 256, 0, stream>>>(ealb, UaT, bu, kpb, B_ * S_, 512, 512);
    transpose_kp<<<512, 256, 0, stream>>>(kpb, kpT);
    init_state<<<1024, 256, 0, stream>>>(e_h, e_c, cst, hcbf, xeh, E);

    P pp;
    pp.target = target; pp.E = E; pp.bv = bv; pp.ba = ba; pp.bout = b_out;
    pp.vab = vab;
    pp.ealb = ealb; pp.kpT = kpT; pp.WaT = WaT; pp.WehT = WehT; pp.WctxT = WctxT; pp.WoutT = WoutT;
    pp.bcat = bcat; pp.qbf = qbf; pp.xeh = xeh; pp.ctxb = ctxb; pp.gpb = gpb;
    pp.hcbf = hcbf; pp.h2bf = h2bf; pp.cst = cst;
    pp.out_logits = out_logits; pp.out_attn = out_attn;

    // q(0) + pgate(0) from initial state
    kC<<<256, 256, 0, stream>>>(pp);

    // ---- sequential decode: A(attn ∥ out_{t-1}) -> B(fgate+LSTM) -> C(q ∥ pgate) ----
    for (int t = 0; t < T_; ++t) {
        kA<<<520, 256, 0, stream>>>(pp, t);
        kB<<<256, 256, 0, stream>>>(pp, t);
        kC<<<256, 256, 0, stream>>>(pp);
    }
    kOutLast<<<8, 256, 0, stream>>>(pp, T_ - 1);
    (void)n_in; (void)in_sizes; (void)out_size;
}

// Round 9
// 6449.291 us; speedup vs baseline: 1.1539x; 1.0090x over previous
//
#include <hip/hip_runtime.h>

#define B_ 512
#define S_ 128
#define T_ 128
#define D_ 512
#define V_ 128
#define LDW 72   // 144B row stride -> 2-way LDS bank aliasing on ds_read_b128 (free)

typedef __attribute__((ext_vector_type(8))) short s16x8;
typedef __attribute__((ext_vector_type(4))) short s16x4;
typedef __attribute__((ext_vector_type(4))) float f32x4;

__device__ __forceinline__ float b2f(unsigned short h) {
    union { unsigned int u; float f; } x; x.u = ((unsigned int)h) << 16; return x.f;
}
__device__ __forceinline__ unsigned short f2b(float f) {
    union { float f; unsigned int u; } x; x.f = f;
    unsigned int u = x.u; u += 0x7FFFu + ((u >> 16) & 1u);
    return (unsigned short)(u >> 16);
}
#if __has_builtin(__builtin_amdgcn_rcpf)
__device__ __forceinline__ float rcp_f(float x) { return __builtin_amdgcn_rcpf(x); }
#else
__device__ __forceinline__ float rcp_f(float x) { return 1.0f / x; }
#endif
__device__ __forceinline__ float sigm(float x) { return rcp_f(1.0f + __expf(-x)); }
__device__ __forceinline__ float tanh_fast(float x) {
    float e = __expf(2.0f * fabsf(x));          // e^{2|x|}; inf -> rcp=0 -> 1.0
    float r = 1.0f - 2.0f * rcp_f(e + 1.0f);
    return copysignf(r, x);
}

// ---------------- fp8 (OCP e4m3) encode/decode ----------------
#if __has_builtin(__builtin_amdgcn_cvt_f32_fp8)
__device__ __forceinline__ f32x4 fp8x4_dec(unsigned w) {
    f32x4 r;
    r[0] = __builtin_amdgcn_cvt_f32_fp8(w, 0);
    r[1] = __builtin_amdgcn_cvt_f32_fp8(w, 1);
    r[2] = __builtin_amdgcn_cvt_f32_fp8(w, 2);
    r[3] = __builtin_amdgcn_cvt_f32_fp8(w, 3);
    return r;
}
#else
__device__ __forceinline__ float fp8_dec_sw(unsigned w, int j) {
    unsigned char v = (w >> (8 * j)) & 0xFF;
    unsigned s = v >> 7, e = (v >> 3) & 0xF, m = v & 7;
    float r = (e == 0) ? ldexpf((float)m, -9) : ldexpf((float)(8 + m), (int)e - 10);
    return s ? -r : r;
}
__device__ __forceinline__ f32x4 fp8x4_dec(unsigned w) {
    f32x4 r;
    r[0] = fp8_dec_sw(w, 0); r[1] = fp8_dec_sw(w, 1);
    r[2] = fp8_dec_sw(w, 2); r[3] = fp8_dec_sw(w, 3);
    return r;
}
#endif

#if __has_builtin(__builtin_amdgcn_cvt_pk_fp8_f32)
__device__ __forceinline__ unsigned pk_fp8(float a, float b, float c, float d) {
    int r = 0;
    r = __builtin_amdgcn_cvt_pk_fp8_f32(a, b, r, false);
    r = __builtin_amdgcn_cvt_pk_fp8_f32(c, d, r, true);
    return (unsigned)r;
}
#else
__device__ __forceinline__ unsigned char f32_to_fp8_sw(float x) {
    unsigned s = x < 0.f ? 0x80u : 0u; float a = fabsf(x);
    if (a != a) return (unsigned char)(s | 0x7F);
    if (a >= 448.f) return (unsigned char)(s | 0x7E);
    if (a < 0.001953125f) { int m = (int)rintf(a * 512.0f); return (unsigned char)(s | (m > 7 ? 0x08 : m)); }
    int e; float fr = frexpf(a, &e);
    int m = (int)rintf(fr * 16.0f - 8.0f);
    int ee = e - 1 + 7;
    if (m == 8) { m = 0; ee += 1; }
    if (ee <= 0) { int mm = (int)rintf(a * 512.f); return (unsigned char)(s | (mm > 7 ? 0x08 : mm)); }
    if (ee >= 16) return (unsigned char)(s | 0x7E);
    return (unsigned char)(s | (ee << 3) | m);
}
__device__ __forceinline__ unsigned pk_fp8(float a, float b, float c, float d) {
    return (unsigned)f32_to_fp8_sw(a) | ((unsigned)f32_to_fp8_sw(b) << 8)
         | ((unsigned)f32_to_fp8_sw(c) << 16) | ((unsigned)f32_to_fp8_sw(d) << 24);
}
#endif

struct P {
    const int* target;
    const float* E; const float* bv; const float* ba; const float* bout;
    const short* vab;
    const unsigned char* ea8; const unsigned char* kp8;
    const short* WaT; const short* WehT; const short* WctxT; const short* WoutT;
    const float* bcat;
    short* qbf; short* xeh; short* ctxb; short* gpb;
    short* hcbf; short* h2bf; float* cst;
    float* out_logits; float* out_attn;
};

struct AttnS { float scp[4][64]; float wbuf[S_]; float cpart[4][D_]; };
struct OutS  { short As[64][LDW]; short Bs[128][LDW]; };
struct PG2   { short As[128][LDW]; short Bs[64][LDW]; };
struct GateS { short As[64][LDW]; short Bs[64][LDW]; float gt[64][65]; };
union SharedA { AttnS a; OutS o; };
union SharedC { OutS o; PG2 g; };

// ---------------- attention: fp8 K/e_all, lane-per-s coalesced scores + wave0 softmax + ctx --------
// kp8 layout: [b][g=d/16][s][16B] -> lane l (s=l) reads 16B; 64 lanes = 1KB contiguous per instr
__device__ __forceinline__ void attn_phase(const P& p, AttnS& sh, int b, int step)
{
    const int t = threadIdx.x, lane = t & 63, wave = t >> 6;
    {
        const int sg = wave & 1, dh = wave >> 1;     // s-group, d-half
        const int s = sg * 64 + lane;
        const unsigned char* kb = p.kp8 + (size_t)b * (S_ * D_);
        const short* qv = p.qbf + (size_t)b * D_;
        float acc = 0.f;
        #pragma unroll 4
        for (int i = 0; i < 16; ++i) {
            int g = dh * 16 + i;
            uint4 kw = *(const uint4*)(kb + ((size_t)g * 128 + s) * 16);
            const short* qg = qv + g * 16;
            const short* vg = p.vab + g * 16;
            s16x8 q0 = *(const s16x8*)(qg), q1 = *(const s16x8*)(qg + 8);
            s16x8 v0 = *(const s16x8*)(vg), v1 = *(const s16x8*)(vg + 8);
            f32x4 ka = fp8x4_dec(kw.x), kb4 = fp8x4_dec(kw.y);
            f32x4 kc = fp8x4_dec(kw.z), kd = fp8x4_dec(kw.w);
            #pragma unroll
            for (int j = 0; j < 4; ++j) {
                acc += tanh_fast(b2f((unsigned short)q0[j])     + ka[j])  * b2f((unsigned short)v0[j]);
                acc += tanh_fast(b2f((unsigned short)q0[4 + j]) + kb4[j]) * b2f((unsigned short)v0[4 + j]);
                acc += tanh_fast(b2f((unsigned short)q1[j])     + kc[j])  * b2f((unsigned short)v1[j]);
                acc += tanh_fast(b2f((unsigned short)q1[4 + j]) + kd[j])  * b2f((unsigned short)v1[4 + j]);
            }
        }
        sh.scp[wave][lane] = acc;
    }
    __syncthreads();
    if (wave == 0) {
        const float bvv = p.bv[0];
        float v0 = sh.scp[0][lane] + sh.scp[2][lane] + bvv;   // s = lane
        float v1 = sh.scp[1][lane] + sh.scp[3][lane] + bvv;   // s = lane + 64
        float m = fmaxf(v0, v1);
        #pragma unroll
        for (int o = 32; o >= 1; o >>= 1) m = fmaxf(m, __shfl_xor(m, o));
        float e0 = __expf(v0 - m), e1 = __expf(v1 - m);
        float su = e0 + e1;
        #pragma unroll
        for (int o = 32; o >= 1; o >>= 1) su += __shfl_xor(su, o);
        float inv = rcp_f(su);
        float w0 = e0 * inv, w1 = e1 * inv;
        sh.wbuf[lane] = w0; sh.wbuf[lane + 64] = w1;
        float* ao = p.out_attn + ((size_t)b * T_ + step) * S_;
        ao[lane] = w0; ao[lane + 64] = w1;
    }
    __syncthreads();
    {
        const int d0 = lane * 8;
        f32x4 aA = {0.f,0.f,0.f,0.f}, aB = {0.f,0.f,0.f,0.f};
        const unsigned char* eb = p.ea8 + (size_t)b * S_ * D_ + d0;
        #pragma unroll 4
        for (int i = 0; i < 32; ++i) {
            int s = wave * 32 + i;
            float wv = sh.wbuf[s];
            uint2 ev = *(const uint2*)(eb + (size_t)s * D_);
            f32x4 ex = fp8x4_dec(ev.x), ey = fp8x4_dec(ev.y);
            #pragma unroll
            for (int j = 0; j < 4; ++j) aA[j] += wv * ex[j];
            #pragma unroll
            for (int j = 0; j < 4; ++j) aB[j] += wv * ey[j];
        }
        *(f32x4*)&sh.cpart[wave][d0]     = aA;
        *(f32x4*)&sh.cpart[wave][d0 + 4] = aB;
    }
    __syncthreads();
    {
        int dd = t * 2;
        float v0 = sh.cpart[0][dd]   + sh.cpart[1][dd]   + sh.cpart[2][dd]   + sh.cpart[3][dd];
        float v1 = sh.cpart[0][dd+1] + sh.cpart[1][dd+1] + sh.cpart[2][dd+1] + sh.cpart[3][dd+1];
        short2 o2; o2.x = (short)f2b(v0); o2.y = (short)f2b(v1);
        *(short2*)(p.ctxb + (size_t)b * D_ + dd) = o2;
    }
}

// ---------------- partial gate GEMM 128x64: Gp = [emb,h] @ W_eh^T + bcat (K=1024) -> bf16 ----------
__device__ __forceinline__ void pgate_phase(const P& p, PG2& sh, int bid2)
{
    const int t = threadIdx.x, lane = t & 63, wave = t >> 6;
    const int lrow = lane & 15, kq = lane >> 4;
    const int m0 = (bid2 >> 5) * 128, n0 = (bid2 & 31) * 64;
    const int K = 1024;
    f32x4 acc[2][4] = {};
    for (int k0 = 0; k0 < K; k0 += 64) {
        s16x8 va[4], vb[2];
        #pragma unroll
        for (int r = 0; r < 4; ++r) {
            int idx = r * 256 + t, row = idx >> 3, seg = idx & 7;
            va[r] = *(const s16x8*)(p.xeh + (size_t)(m0 + row) * K + k0 + seg * 8);
        }
        #pragma unroll
        for (int r = 0; r < 2; ++r) {
            int idx = r * 256 + t, row = idx >> 3, seg = idx & 7;
            vb[r] = *(const s16x8*)(p.WehT + (size_t)(n0 + row) * K + k0 + seg * 8);
        }
        __syncthreads();
        #pragma unroll
        for (int r = 0; r < 4; ++r) {
            int idx = r * 256 + t, row = idx >> 3, seg = idx & 7;
            *(s16x8*)(&sh.As[row][seg * 8]) = va[r];
        }
        #pragma unroll
        for (int r = 0; r < 2; ++r) {
            int idx = r * 256 + t, row = idx >> 3, seg = idx & 7;
            *(s16x8*)(&sh.Bs[row][seg * 8]) = vb[r];
        }
        __syncthreads();
        #pragma unroll
        for (int kk = 0; kk < 64; kk += 32) {
            s16x8 af[2], bf[4];
            af[0] = *(const s16x8*)(&sh.As[wave * 32 + lrow][kk + kq * 8]);
            af[1] = *(const s16x8*)(&sh.As[wave * 32 + 16 + lrow][kk + kq * 8]);
            #pragma unroll
            for (int f = 0; f < 4; ++f)
                bf[f] = *(const s16x8*)(&sh.Bs[f * 16 + lrow][kk + kq * 8]);
            #pragma unroll
            for (int m2 = 0; m2 < 2; ++m2)
                #pragma unroll
                for (int n2 = 0; n2 < 4; ++n2)
                    acc[m2][n2] = __builtin_amdgcn_mfma_f32_16x16x32_bf16(af[m2], bf[n2], acc[m2][n2], 0, 0, 0);
        }
    }
    #pragma unroll
    for (int m2 = 0; m2 < 2; ++m2)
        #pragma unroll
        for (int n2 = 0; n2 < 4; ++n2) {
            int col = n0 + n2 * 16 + lrow;
            float bvv = p.bcat[col];
            #pragma unroll
            for (int j = 0; j < 4; ++j) {
                int row = m0 + wave * 32 + m2 * 16 + kq * 4 + j;
                p.gpb[(size_t)row * 2048 + col] = (short)f2b(acc[m2][n2][j] + bvv);
            }
        }
}

// ---------------- final gate GEMM (K=512, ctx) + Gp + fused LSTM ----------------
__device__ __forceinline__ void fgate_phase(const P& p, GateS& sh, int bid, int step)
{
    const int t = threadIdx.x, lane = t & 63, wave = t >> 6;
    const int wr = wave >> 1, wc = wave & 1;
    const int lrow = lane & 15, kq = lane >> 4;
    const int srow = t >> 3, sseg = t & 7;
    const int m0 = (bid >> 5) * 64, n0 = (bid & 31) * 64;
    f32x4 acc[2][2] = {};
    for (int k0 = 0; k0 < 512; k0 += 64) {
        s16x8 va0 = *(const s16x8*)(p.ctxb + (size_t)(m0 + srow) * 512 + k0 + sseg * 8);
        s16x8 va1 = *(const s16x8*)(p.ctxb + (size_t)(m0 + srow + 32) * 512 + k0 + sseg * 8);
        s16x8 vb0 = *(const s16x8*)(p.WctxT + (size_t)(n0 + srow) * 512 + k0 + sseg * 8);
        s16x8 vb1 = *(const s16x8*)(p.WctxT + (size_t)(n0 + srow + 32) * 512 + k0 + sseg * 8);
        __syncthreads();
        *(s16x8*)(&sh.As[srow][sseg * 8]) = va0;
        *(s16x8*)(&sh.As[srow + 32][sseg * 8]) = va1;
        *(s16x8*)(&sh.Bs[srow][sseg * 8]) = vb0;
        *(s16x8*)(&sh.Bs[srow + 32][sseg * 8]) = vb1;
        __syncthreads();
        #pragma unroll
        for (int kk = 0; kk < 64; kk += 32) {
            s16x8 af0 = *(const s16x8*)(&sh.As[wr * 32 + lrow][kk + kq * 8]);
            s16x8 af1 = *(const s16x8*)(&sh.As[wr * 32 + 16 + lrow][kk + kq * 8]);
            s16x8 bf0 = *(const s16x8*)(&sh.Bs[wc * 32 + lrow][kk + kq * 8]);
            s16x8 bf1 = *(const s16x8*)(&sh.Bs[wc * 32 + 16 + lrow][kk + kq * 8]);
            acc[0][0] = __builtin_amdgcn_mfma_f32_16x16x32_bf16(af0, bf0, acc[0][0], 0, 0, 0);
            acc[0][1] = __builtin_amdgcn_mfma_f32_16x16x32_bf16(af0, bf1, acc[0][1], 0, 0, 0);
            acc[1][0] = __builtin_amdgcn_mfma_f32_16x16x32_bf16(af1, bf0, acc[1][0], 0, 0, 0);
            acc[1][1] = __builtin_amdgcn_mfma_f32_16x16x32_bf16(af1, bf1, acc[1][1], 0, 0, 0);
        }
    }
    #pragma unroll
    for (int m2 = 0; m2 < 2; ++m2)
        #pragma unroll
        for (int n2 = 0; n2 < 2; ++n2) {
            int cl = wc * 32 + n2 * 16 + lrow;
            #pragma unroll
            for (int j = 0; j < 4; ++j) {
                int rl = wr * 32 + m2 * 16 + kq * 4 + j;
                sh.gt[rl][cl] = acc[m2][n2][j]
                              + b2f((unsigned short)p.gpb[(size_t)(m0 + rl) * 2048 + n0 + cl]);
            }
        }
    __syncthreads();
    const int rl4 = t >> 4, dl = t & 15;
    #pragma unroll
    for (int pass = 0; pass < 4; ++pass) {
        int row = pass * 16 + rl4;
        int b = m0 + row;
        int d = (n0 >> 2) + dl;
        float gi = sh.gt[row][dl * 4 + 0];
        float gf = sh.gt[row][dl * 4 + 1];
        float gg = sh.gt[row][dl * 4 + 2];
        float go = sh.gt[row][dl * 4 + 3];
        float cv = p.cst[(size_t)b * D_ + d];
        float c2 = sigm(gf) * cv + sigm(gi) * tanh_fast(gg);
        float h2 = sigm(go) * tanh_fast(c2);
        p.cst[(size_t)b * D_ + d] = c2;
        p.hcbf[(size_t)b * D_ + d] = (short)f2b(h2 + c2);
        p.h2bf[(size_t)b * D_ + d] = (short)f2b(h2);
        p.xeh[(size_t)b * 1024 + 512 + d] = (short)f2b(h2);
        int tok = p.target[b * T_ + step];
        p.xeh[(size_t)b * 1024 + d] = (short)f2b(p.E[(size_t)tok * D_ + d]);
    }
}

// ---------------- q GEMM 64x32 tiles -> bf16 q ----------------
__device__ __forceinline__ void q_phase(const P& p, OutS& sh, int bid)
{
    const int t = threadIdx.x, lane = t & 63, wave = t >> 6;
    const int lrow = lane & 15, kq = lane >> 4;
    const int srow = t >> 3, sseg = t & 7;
    const int m0 = (bid >> 4) * 64, n0 = (bid & 15) * 32;
    f32x4 acc0 = {}, acc1 = {};
    for (int k0 = 0; k0 < 512; k0 += 64) {
        s16x8 va0 = *(const s16x8*)(p.hcbf + (size_t)(m0 + srow) * 512 + k0 + sseg * 8);
        s16x8 va1 = *(const s16x8*)(p.hcbf + (size_t)(m0 + srow + 32) * 512 + k0 + sseg * 8);
        int brow = n0 + (srow & 31);
        s16x8 vb0 = *(const s16x8*)(p.WaT + (size_t)brow * 512 + k0 + sseg * 8);
        __syncthreads();
        *(s16x8*)(&sh.As[srow][sseg * 8]) = va0;
        *(s16x8*)(&sh.As[srow + 32][sseg * 8]) = va1;
        if (srow < 32) *(s16x8*)(&sh.Bs[srow][sseg * 8]) = vb0;
        __syncthreads();
        #pragma unroll
        for (int kk = 0; kk < 64; kk += 32) {
            s16x8 af  = *(const s16x8*)(&sh.As[wave * 16 + lrow][kk + kq * 8]);
            s16x8 bf0 = *(const s16x8*)(&sh.Bs[lrow][kk + kq * 8]);
            s16x8 bf1 = *(const s16x8*)(&sh.Bs[16 + lrow][kk + kq * 8]);
            acc0 = __builtin_amdgcn_mfma_f32_16x16x32_bf16(af, bf0, acc0, 0, 0, 0);
            acc1 = __builtin_amdgcn_mfma_f32_16x16x32_bf16(af, bf1, acc1, 0, 0, 0);
        }
    }
    #pragma unroll
    for (int n2 = 0; n2 < 2; ++n2) {
        int col = n0 + n2 * 16 + lrow;
        float bvv = p.ba[col];
        f32x4 av = n2 ? acc1 : acc0;
        #pragma unroll
        for (int j = 0; j < 4; ++j) {
            int row = m0 + wave * 16 + kq * 4 + j;
            p.qbf[(size_t)row * 512 + col] = (short)f2b(av[j] + bvv);
        }
    }
}

// ---------------- out GEMM (M=512,N=128,K=512) + fused log_softmax ----------------
__device__ __forceinline__ void out_phase(const P& p, OutS& sh, int obid, int step)
{
    const int t = threadIdx.x, lane = t & 63, wave = t >> 6;
    const int lrow = lane & 15, kq = lane >> 4;
    const int srow = t >> 3, sseg = t & 7;
    const int m0 = obid * 64;
    f32x4 acc[8] = {};
    for (int k0 = 0; k0 < 512; k0 += 64) {
        s16x8 va0 = *(const s16x8*)(p.h2bf + (size_t)(m0 + srow) * 512 + k0 + sseg * 8);
        s16x8 va1 = *(const s16x8*)(p.h2bf + (size_t)(m0 + srow + 32) * 512 + k0 + sseg * 8);
        s16x8 vb[4];
        #pragma unroll
        for (int p4 = 0; p4 < 4; ++p4)
            vb[p4] = *(const s16x8*)(p.WoutT + (size_t)(srow + p4 * 32) * 512 + k0 + sseg * 8);
        __syncthreads();
        *(s16x8*)(&sh.As[srow][sseg * 8]) = va0;
        *(s16x8*)(&sh.As[srow + 32][sseg * 8]) = va1;
        #pragma unroll
        for (int p4 = 0; p4 < 4; ++p4) *(s16x8*)(&sh.Bs[srow + p4 * 32][sseg * 8]) = vb[p4];
        __syncthreads();
        #pragma unroll
        for (int kk = 0; kk < 64; kk += 32) {
            s16x8 a = *(const s16x8*)(&sh.As[wave * 16 + lrow][kk + kq * 8]);
            #pragma unroll
            for (int f = 0; f < 8; ++f) {
                s16x8 b = *(const s16x8*)(&sh.Bs[f * 16 + lrow][kk + kq * 8]);
                acc[f] = __builtin_amdgcn_mfma_f32_16x16x32_bf16(a, b, acc[f], 0, 0, 0);
            }
        }
    }
    float colb[8];
    #pragma unroll
    for (int f = 0; f < 8; ++f) colb[f] = p.bout[f * 16 + lrow];
    #pragma unroll
    for (int j = 0; j < 4; ++j) {
        float v[8]; float mx = -1e30f;
        #pragma unroll
        for (int f = 0; f < 8; ++f) { v[f] = acc[f][j] + colb[f]; mx = fmaxf(mx, v[f]); }
        #pragma unroll
        for (int o = 1; o < 16; o <<= 1) mx = fmaxf(mx, __shfl_xor(mx, o));
        float sum = 0.f;
        #pragma unroll
        for (int f = 0; f < 8; ++f) sum += __expf(v[f] - mx);
        #pragma unroll
        for (int o = 1; o < 16; o <<= 1) sum += __shfl_xor(sum, o);
        float lse = mx + __logf(sum);
        int row = m0 + wave * 16 + kq * 4 + j;
        float* orow = p.out_logits + ((size_t)row * T_ + step) * V_;
        #pragma unroll
        for (int f = 0; f < 8; ++f) orow[f * 16 + lrow] = v[f] - lse;
    }
}

// ---------------- per-step dispatches ----------------
// A: attn(0..511) | out_{t-1}(512..519, skipped at t=0)
__global__ __launch_bounds__(256, 2) void kA(P p, int step) {
    __shared__ SharedA sh;
    const int bid = blockIdx.x;
    if (bid < 512)     attn_phase(p, sh.a, bid, step);
    else if (step > 0) out_phase(p, sh.o, bid - 512, step - 1);
}
__global__ __launch_bounds__(256, 2) void kB(P p, int step) {
    __shared__ GateS sh;
    fgate_phase(p, sh, blockIdx.x, step);
}
// C: q(0..127) | pgate(128..255)
__global__ __launch_bounds__(256, 2) void kC(P p) {
    __shared__ SharedC sh;
    const int bid = blockIdx.x;
    if (bid < 128) q_phase(p, sh.o, bid);
    else           pgate_phase(p, sh.g, bid - 128);
}
__global__ __launch_bounds__(256, 2) void kOutLast(P p, int step) {
    __shared__ OutS sh;
    out_phase(p, sh, blockIdx.x, step);
}

// ---------------- precompute kernels ----------------
__global__ __launch_bounds__(256)
void gemm64(const short* __restrict__ A, const short* __restrict__ Bt,
            const float* __restrict__ bias, short* __restrict__ Cp,
            int M, int N, int K)
{
    __shared__ __align__(16) short As[64][LDW];
    __shared__ __align__(16) short Bs[64][LDW];
    const int t = threadIdx.x;
    const int lane = t & 63, wave = t >> 6;
    const int wr = wave >> 1, wc = wave & 1;
    const int lrow = lane & 15, kq = lane >> 4;
    const int m0 = blockIdx.y * 64, n0 = blockIdx.x * 64;
    const int srow = t >> 3, sseg = t & 7;
    f32x4 acc[2][2] = {};
    for (int k0 = 0; k0 < K; k0 += 64) {
        s16x8 va0 = *(const s16x8*)(A + (size_t)(m0 + srow) * K + k0 + sseg * 8);
        s16x8 va1 = *(const s16x8*)(A + (size_t)(m0 + srow + 32) * K + k0 + sseg * 8);
        s16x8 vb0 = *(const s16x8*)(Bt + (size_t)(n0 + srow) * K + k0 + sseg * 8);
        s16x8 vb1 = *(const s16x8*)(Bt + (size_t)(n0 + srow + 32) * K + k0 + sseg * 8);
        __syncthreads();
        *(s16x8*)(&As[srow][sseg * 8]) = va0;
        *(s16x8*)(&As[srow + 32][sseg * 8]) = va1;
        *(s16x8*)(&Bs[srow][sseg * 8]) = vb0;
        *(s16x8*)(&Bs[srow + 32][sseg * 8]) = vb1;
        __syncthreads();
        for (int kk = 0; kk < 64; kk += 32) {
            s16x8 af[2], bf[2];
            af[0] = *(const s16x8*)(&As[wr * 32 + lrow][kk + kq * 8]);
            af[1] = *(const s16x8*)(&As[wr * 32 + 16 + lrow][kk + kq * 8]);
            bf[0] = *(const s16x8*)(&Bs[wc * 32 + lrow][kk + kq * 8]);
            bf[1] = *(const s16x8*)(&Bs[wc * 32 + 16 + lrow][kk + kq * 8]);
            for (int m2 = 0; m2 < 2; ++m2)
                for (int n2 = 0; n2 < 2; ++n2)
                    acc[m2][n2] = __builtin_amdgcn_mfma_f32_16x16x32_bf16(af[m2], bf[n2], acc[m2][n2], 0, 0, 0);
        }
    }
    for (int m2 = 0; m2 < 2; ++m2)
        for (int n2 = 0; n2 < 2; ++n2) {
            int col = n0 + wc * 32 + n2 * 16 + lrow;
            float bvv = bias ? bias[col] : 0.0f;
            for (int j = 0; j < 4; ++j) {
                int row = m0 + wr * 32 + m2 * 16 + kq * 4 + j;
                Cp[(size_t)row * N + col] = (short)f2b(acc[m2][n2][j] + bvv);
            }
        }
}

// kpb[b][s][d] (bf16) -> kp8[b][g=d/16][s][16B] (fp8)
__global__ __launch_bounds__(256)
void transpose_kp8(const short* __restrict__ in, unsigned char* __restrict__ out)
{
    const int b = blockIdx.x, t = threadIdx.x;
    const size_t ibase = (size_t)b * (S_ * D_);
    for (int k = t; k < 32 * S_; k += 256) {
        int g = k >> 7, s = k & 127;
        const short* src = in + ibase + (size_t)s * D_ + g * 16;
        unsigned w[4];
        #pragma unroll
        for (int q4 = 0; q4 < 4; ++q4) {
            w[q4] = pk_fp8(b2f((unsigned short)src[q4 * 4 + 0]), b2f((unsigned short)src[q4 * 4 + 1]),
                           b2f((unsigned short)src[q4 * 4 + 2]), b2f((unsigned short)src[q4 * 4 + 3]));
        }
        uint4 o; o.x = w[0]; o.y = w[1]; o.z = w[2]; o.w = w[3];
        *(uint4*)(out + ibase + ((size_t)g * S_ + s) * 16) = o;
    }
}

__global__ __launch_bounds__(256)
void cast_fp8_v4(const float* __restrict__ in, unsigned char* __restrict__ out, int n4)
{
    int i = blockIdx.x * 256 + threadIdx.x;
    int stride = gridDim.x * 256;
    for (; i < n4; i += stride) {
        f32x4 v = ((const f32x4*)in)[i];
        ((unsigned*)out)[i] = pk_fp8(v[0], v[1], v[2], v[3]);
    }
}

__global__ __launch_bounds__(256)
void init_state(const float* __restrict__ e_h, const float* __restrict__ e_c,
                float* __restrict__ c, short* __restrict__ hcbf,
                short* __restrict__ xeh, const float* __restrict__ E)
{
    int gid = blockIdx.x * 256 + threadIdx.x;
    int b = gid >> 9, d = gid & 511;
    float h0 = e_h[gid], c0 = e_c[gid];
    c[gid] = c0;
    hcbf[gid] = (short)f2b(h0 + c0);
    xeh[(size_t)b * 1024 + 512 + d] = (short)f2b(h0);
    xeh[(size_t)b * 1024 + d] = (short)f2b(E[d]);   // token 0 (SOS)
}

__global__ __launch_bounds__(256)
void transpose_cast(const float* __restrict__ in, short* __restrict__ out,
                    int N, int ostride, int koff, int gate_perm)
{
    __shared__ float tile[64][65];
    int t = threadIdx.x;
    int n0 = blockIdx.x * 64, k0 = blockIdx.y * 64;
    int cc = t & 63, r4 = t >> 6;
    for (int i = 0; i < 16; ++i) {
        int r = i * 4 + r4;
        tile[r][cc] = in[(size_t)(k0 + r) * N + n0 + cc];
    }
    __syncthreads();
    for (int i = 0; i < 16; ++i) {
        int nr = i * 4 + r4;
        int ng = n0 + nr;
        int np = gate_perm ? ((ng & 511) * 4 + (ng >> 9)) : ng;
        out[(size_t)np * ostride + koff + k0 + cc] = (short)f2b(tile[cc][nr]);
    }
}

__global__ __launch_bounds__(256)
void cast_bf16_v4(const float* __restrict__ in, short* __restrict__ out, int n4)
{
    int i = blockIdx.x * 256 + threadIdx.x;
    int stride = gridDim.x * 256;
    for (; i < n4; i += stride) {
        f32x4 v = ((const f32x4*)in)[i];
        s16x4 o;
        for (int j = 0; j < 4; ++j) o[j] = (short)f2b(v[j]);
        ((s16x4*)out)[i] = o;
    }
}

__global__ __launch_bounds__(256)
void make_bcat(const float* __restrict__ b_ih, const float* __restrict__ b_hh, float* __restrict__ bcat)
{
    int i = blockIdx.x * 256 + threadIdx.x;
    if (i < 2048) {
        int np = (i & 511) * 4 + (i >> 9);
        bcat[np] = b_ih[i] + b_hh[i];
    }
}

extern "C" void kernel_launch(void* const* d_in, const int* in_sizes, int n_in,
                              void* d_out, int out_size, void* d_ws, size_t ws_size,
                              hipStream_t stream)
{
    const float* e_all  = (const float*)d_in[0];
    const float* e_h    = (const float*)d_in[1];
    const float* e_c    = (const float*)d_in[2];
    const int*   target = (const int*)d_in[3];
    const float* E      = (const float*)d_in[4];
    const float* Wa     = (const float*)d_in[5];
    const float* ba     = (const float*)d_in[6];
    const float* Ua     = (const float*)d_in[7];
    const float* bu     = (const float*)d_in[8];
    const float* Va     = (const float*)d_in[9];
    const float* bv     = (const float*)d_in[10];
    const float* W_ih   = (const float*)d_in[11];
    const float* b_ih   = (const float*)d_in[12];
    const float* W_hh   = (const float*)d_in[13];
    const float* b_hh   = (const float*)d_in[14];
    const float* W_out  = (const float*)d_in[15];
    const float* b_out  = (const float*)d_in[16];

    char* ws = (char*)d_ws;
    size_t off = 0;
    auto alloc = [&](size_t bytes) { void* p = ws + off; off += (bytes + 255) & ~255ull; return p; };
    short* ealb  = (short*)alloc((size_t)B_ * S_ * D_ * 2);
    short* kpb   = (short*)alloc((size_t)B_ * S_ * D_ * 2);          // bf16 scratch (pre-fp8)
    unsigned char* kp8 = (unsigned char*)alloc((size_t)B_ * S_ * D_); // fp8 [b][d/16][s][16]
    unsigned char* ea8 = (unsigned char*)alloc((size_t)B_ * S_ * D_); // fp8 [b][s][d]
    short* WaT   = (short*)alloc((size_t)D_ * D_ * 2);
    short* UaT   = (short*)alloc((size_t)D_ * D_ * 2);
    short* WehT  = (short*)alloc((size_t)2048 * 1024 * 2);
    short* WctxT = (short*)alloc((size_t)2048 * 512 * 2);
    short* WoutT = (short*)alloc((size_t)V_ * D_ * 2);
    float* bcat  = (float*)alloc(2048 * 4);
    short* qbf   = (short*)alloc((size_t)B_ * D_ * 2);
    short* vab   = (short*)alloc((size_t)D_ * 2);
    short* xeh   = (short*)alloc((size_t)B_ * 1024 * 2);
    short* ctxb  = (short*)alloc((size_t)B_ * D_ * 2);
    short* gpb   = (short*)alloc((size_t)B_ * 2048 * 2);
    short* hcbf  = (short*)alloc((size_t)B_ * D_ * 2);
    short* h2bf  = (short*)alloc((size_t)B_ * D_ * 2);
    float* cst   = (float*)alloc((size_t)B_ * D_ * 4);
    if (off > ws_size) return;

    float* out_logits = (float*)d_out;                        // [B,T,V]
    float* out_attn   = (float*)d_out + (size_t)B_ * T_ * V_; // [B,T,S]

    // ---- precompute ----
    cast_bf16_v4<<<4096, 256, 0, stream>>>(e_all, ealb, B_ * S_ * D_ / 4);
    cast_fp8_v4<<<4096, 256, 0, stream>>>(e_all, ea8, B_ * S_ * D_ / 4);
    cast_bf16_v4<<<1,    256, 0, stream>>>(Va, vab, D_ / 4);
    transpose_cast<<<dim3(8, 8),  256, 0, stream>>>(Wa,  WaT,  512,  512, 0, 0);
    transpose_cast<<<dim3(8, 8),  256, 0, stream>>>(Ua,  UaT,  512,  512, 0, 0);
    transpose_cast<<<dim3(32, 8), 256, 0, stream>>>(W_ih,              WehT,  2048, 1024, 0,   1);
    transpose_cast<<<dim3(32, 8), 256, 0, stream>>>(W_ih + 512 * 2048, WctxT, 2048, 512,  0,   1);
    transpose_cast<<<dim3(32, 8), 256, 0, stream>>>(W_hh,              WehT,  2048, 1024, 512, 1);
    transpose_cast<<<dim3(2, 8),  256, 0, stream>>>(W_out, WoutT, 128, 512, 0, 0);
    make_bcat<<<8, 256, 0, stream>>>(b_ih, b_hh, bcat);
    gemm64<<<dim3(8, 1024), 256, 0, stream>>>(ealb, UaT, bu, kpb, B_ * S_, 512, 512);
    transpose_kp8<<<512, 256, 0, stream>>>(kpb, kp8);
    init_state<<<1024, 256, 0, stream>>>(e_h, e_c, cst, hcbf, xeh, E);

    P pp;
    pp.target = target; pp.E = E; pp.bv = bv; pp.ba = ba; pp.bout = b_out;
    pp.vab = vab;
    pp.ea8 = ea8; pp.kp8 = kp8; pp.WaT = WaT; pp.WehT = WehT; pp.WctxT = WctxT; pp.WoutT = WoutT;
    pp.bcat = bcat; pp.qbf = qbf; pp.xeh = xeh; pp.ctxb = ctxb; pp.gpb = gpb;
    pp.hcbf = hcbf; pp.h2bf = h2bf; pp.cst = cst;
    pp.out_logits = out_logits; pp.out_attn = out_attn;

    // q(0) + pgate(0) from initial state
    kC<<<256, 256, 0, stream>>>(pp);

    // ---- sequential decode: A(attn ∥ out_{t-1}) -> B(fgate+LSTM) -> C(q ∥ pgate) ----
    for (int t = 0; t < T_; ++t) {
        kA<<<520, 256, 0, stream>>>(pp, t);
        kB<<<256, 256, 0, stream>>>(pp, t);
        kC<<<256, 256, 0, stream>>>(pp);
    }
    kOutLast<<<8, 256, 0, stream>>>(pp, T_ - 1);
    (void)n_in; (void)in_sizes; (void)out_size;
}

// Round 10
// 6258.821 us; speedup vs baseline: 1.1890x; 1.0304x over previous
//
#include <hip/hip_runtime.h>

#define B_ 512
#define S_ 128
#define T_ 128
#define D_ 512
#define V_ 128
#define LDW 72   // 144B row stride -> 2-way LDS bank aliasing on ds_read_b128 (free)

typedef __attribute__((ext_vector_type(8))) short s16x8;
typedef __attribute__((ext_vector_type(4))) short s16x4;
typedef __attribute__((ext_vector_type(4))) float f32x4;

__device__ __forceinline__ float b2f(unsigned short h) {
    union { unsigned int u; float f; } x; x.u = ((unsigned int)h) << 16; return x.f;
}
__device__ __forceinline__ unsigned short f2b(float f) {
    union { float f; unsigned int u; } x; x.f = f;
    unsigned int u = x.u; u += 0x7FFFu + ((u >> 16) & 1u);
    return (unsigned short)(u >> 16);
}
#if __has_builtin(__builtin_amdgcn_rcpf)
__device__ __forceinline__ float rcp_f(float x) { return __builtin_amdgcn_rcpf(x); }
#else
__device__ __forceinline__ float rcp_f(float x) { return 1.0f / x; }
#endif
__device__ __forceinline__ float sigm(float x) { return rcp_f(1.0f + __expf(-x)); }
__device__ __forceinline__ float tanh_fast(float x) {
    float e = __expf(2.0f * fabsf(x));          // e^{2|x|}; inf -> rcp=0 -> 1.0
    float r = 1.0f - 2.0f * rcp_f(e + 1.0f);
    return copysignf(r, x);
}
// Pade[3/2] (CF depth 5) tanh: max |err| ~7e-4 with clamp; 1 rcp, no exp.
__device__ __forceinline__ float tanh_pade(float x) {
    float t = x * x;
    float num = x * fmaf(t, 105.0f + t, 945.0f);
    float den = fmaf(t, fmaf(t, 15.0f, 420.0f), 945.0f);
    float r = num * rcp_f(den);
    return fminf(1.0f, fmaxf(-1.0f, r));
}

// ---------------- fp8 (OCP e4m3) encode/decode ----------------
#if __has_builtin(__builtin_amdgcn_cvt_f32_fp8)
__device__ __forceinline__ f32x4 fp8x4_dec(unsigned w) {
    f32x4 r;
    r[0] = __builtin_amdgcn_cvt_f32_fp8(w, 0);
    r[1] = __builtin_amdgcn_cvt_f32_fp8(w, 1);
    r[2] = __builtin_amdgcn_cvt_f32_fp8(w, 2);
    r[3] = __builtin_amdgcn_cvt_f32_fp8(w, 3);
    return r;
}
#else
__device__ __forceinline__ float fp8_dec_sw(unsigned w, int j) {
    unsigned char v = (w >> (8 * j)) & 0xFF;
    unsigned s = v >> 7, e = (v >> 3) & 0xF, m = v & 7;
    float r = (e == 0) ? ldexpf((float)m, -9) : ldexpf((float)(8 + m), (int)e - 10);
    return s ? -r : r;
}
__device__ __forceinline__ f32x4 fp8x4_dec(unsigned w) {
    f32x4 r;
    r[0] = fp8_dec_sw(w, 0); r[1] = fp8_dec_sw(w, 1);
    r[2] = fp8_dec_sw(w, 2); r[3] = fp8_dec_sw(w, 3);
    return r;
}
#endif

#if __has_builtin(__builtin_amdgcn_cvt_pk_fp8_f32)
__device__ __forceinline__ unsigned pk_fp8(float a, float b, float c, float d) {
    int r = 0;
    r = __builtin_amdgcn_cvt_pk_fp8_f32(a, b, r, false);
    r = __builtin_amdgcn_cvt_pk_fp8_f32(c, d, r, true);
    return (unsigned)r;
}
#else
__device__ __forceinline__ unsigned char f32_to_fp8_sw(float x) {
    unsigned s = x < 0.f ? 0x80u : 0u; float a = fabsf(x);
    if (a != a) return (unsigned char)(s | 0x7F);
    if (a >= 448.f) return (unsigned char)(s | 0x7E);
    if (a < 0.001953125f) { int m = (int)rintf(a * 512.0f); return (unsigned char)(s | (m > 7 ? 0x08 : m)); }
    int e; float fr = frexpf(a, &e);
    int m = (int)rintf(fr * 16.0f - 8.0f);
    int ee = e - 1 + 7;
    if (m == 8) { m = 0; ee += 1; }
    if (ee <= 0) { int mm = (int)rintf(a * 512.f); return (unsigned char)(s | (mm > 7 ? 0x08 : mm)); }
    if (ee >= 16) return (unsigned char)(s | 0x7E);
    return (unsigned char)(s | (ee << 3) | m);
}
__device__ __forceinline__ unsigned pk_fp8(float a, float b, float c, float d) {
    return (unsigned)f32_to_fp8_sw(a) | ((unsigned)f32_to_fp8_sw(b) << 8)
         | ((unsigned)f32_to_fp8_sw(c) << 16) | ((unsigned)f32_to_fp8_sw(d) << 24);
}
#endif

struct P {
    const int* target;
    const float* E; const float* bv; const float* ba; const float* bout;
    const short* vab;
    const unsigned char* ea8; const unsigned char* kp8;
    const short* WaT; const short* WehT; const short* WctxT; const short* WoutT;
    const float* bcat;
    short* qbf; short* xeh; short* ctxb; short* gpA; short* gpB;
    short* hcbf; short* h2bf; float* cst;
    float* out_logits; float* out_attn;
};

struct AttnS { float scp[4][64]; float wbuf[S_]; float cpart[4][D_]; };
struct OutS  { short As[64][LDW]; short Bs[128][LDW]; };
struct PG2   { short As[128][LDW]; short Bs[64][LDW]; };
struct GateS { short As[64][LDW]; short Bs[64][LDW]; float gt[64][65]; };
union SharedC { OutS o; PG2 g; };

// ---------------- attention: fp8 K/e_all, lane-per-s coalesced scores + wave0 softmax + ctx --------
// kp8 layout: [b][g=d/16][s][16B] -> lane l (s=l) reads 16B; 64 lanes = 1KB contiguous per instr
__device__ __forceinline__ void attn_phase(const P& p, AttnS& sh, int b, int step)
{
    const int t = threadIdx.x, lane = t & 63, wave = t >> 6;
    {
        const int sg = wave & 1, dh = wave >> 1;     // s-group, d-half
        const int s = sg * 64 + lane;
        const unsigned char* kb = p.kp8 + (size_t)b * (S_ * D_);
        const short* qv = p.qbf + (size_t)b * D_;
        float acc = 0.f;
        #pragma unroll 4
        for (int i = 0; i < 16; ++i) {
            int g = dh * 16 + i;
            uint4 kw = *(const uint4*)(kb + ((size_t)g * 128 + s) * 16);
            const short* qg = qv + g * 16;
            const short* vg = p.vab + g * 16;
            s16x8 q0 = *(const s16x8*)(qg), q1 = *(const s16x8*)(qg + 8);
            s16x8 v0 = *(const s16x8*)(vg), v1 = *(const s16x8*)(vg + 8);
            f32x4 ka = fp8x4_dec(kw.x), kb4 = fp8x4_dec(kw.y);
            f32x4 kc = fp8x4_dec(kw.z), kd = fp8x4_dec(kw.w);
            #pragma unroll
            for (int j = 0; j < 4; ++j) {
                acc += tanh_pade(b2f((unsigned short)q0[j])     + ka[j])  * b2f((unsigned short)v0[j]);
                acc += tanh_pade(b2f((unsigned short)q0[4 + j]) + kb4[j]) * b2f((unsigned short)v0[4 + j]);
                acc += tanh_pade(b2f((unsigned short)q1[j])     + kc[j])  * b2f((unsigned short)v1[j]);
                acc += tanh_pade(b2f((unsigned short)q1[4 + j]) + kd[j])  * b2f((unsigned short)v1[4 + j]);
            }
        }
        sh.scp[wave][lane] = acc;
    }
    __syncthreads();
    if (wave == 0) {
        const float bvv = p.bv[0];
        float v0 = sh.scp[0][lane] + sh.scp[2][lane] + bvv;   // s = lane
        float v1 = sh.scp[1][lane] + sh.scp[3][lane] + bvv;   // s = lane + 64
        float m = fmaxf(v0, v1);
        #pragma unroll
        for (int o = 32; o >= 1; o >>= 1) m = fmaxf(m, __shfl_xor(m, o));
        float e0 = __expf(v0 - m), e1 = __expf(v1 - m);
        float su = e0 + e1;
        #pragma unroll
        for (int o = 32; o >= 1; o >>= 1) su += __shfl_xor(su, o);
        float inv = rcp_f(su);
        float w0 = e0 * inv, w1 = e1 * inv;
        sh.wbuf[lane] = w0; sh.wbuf[lane + 64] = w1;
        float* ao = p.out_attn + ((size_t)b * T_ + step) * S_;
        ao[lane] = w0; ao[lane + 64] = w1;
    }
    __syncthreads();
    {
        const int d0 = lane * 8;
        f32x4 aA = {0.f,0.f,0.f,0.f}, aB = {0.f,0.f,0.f,0.f};
        const unsigned char* eb = p.ea8 + (size_t)b * S_ * D_ + d0;
        #pragma unroll 4
        for (int i = 0; i < 32; ++i) {
            int s = wave * 32 + i;
            float wv = sh.wbuf[s];
            uint2 ev = *(const uint2*)(eb + (size_t)s * D_);
            f32x4 ex = fp8x4_dec(ev.x), ey = fp8x4_dec(ev.y);
            #pragma unroll
            for (int j = 0; j < 4; ++j) aA[j] += wv * ex[j];
            #pragma unroll
            for (int j = 0; j < 4; ++j) aB[j] += wv * ey[j];
        }
        *(f32x4*)&sh.cpart[wave][d0]     = aA;
        *(f32x4*)&sh.cpart[wave][d0 + 4] = aB;
    }
    __syncthreads();
    {
        int dd = t * 2;
        float v0 = sh.cpart[0][dd]   + sh.cpart[1][dd]   + sh.cpart[2][dd]   + sh.cpart[3][dd];
        float v1 = sh.cpart[0][dd+1] + sh.cpart[1][dd+1] + sh.cpart[2][dd+1] + sh.cpart[3][dd+1];
        short2 o2; o2.x = (short)f2b(v0); o2.y = (short)f2b(v1);
        *(short2*)(p.ctxb + (size_t)b * D_ + dd) = o2;
    }
}

// -------- partial gate GEMM 128x64 (split-K): Gp = [emb,h][koff:koff+512] @ W_eh^T (+bcat) -> bf16 --
__device__ __forceinline__ void pgate_phase(const P& p, PG2& sh, int bid2, int koff,
                                            short* __restrict__ gpp, bool addb)
{
    const int t = threadIdx.x, lane = t & 63, wave = t >> 6;
    const int lrow = lane & 15, kq = lane >> 4;
    const int m0 = (bid2 >> 5) * 128, n0 = (bid2 & 31) * 64;
    f32x4 acc[2][4] = {};
    for (int k0 = 0; k0 < 512; k0 += 64) {
        s16x8 va[4], vb[2];
        #pragma unroll
        for (int r = 0; r < 4; ++r) {
            int idx = r * 256 + t, row = idx >> 3, seg = idx & 7;
            va[r] = *(const s16x8*)(p.xeh + (size_t)(m0 + row) * 1024 + koff + k0 + seg * 8);
        }
        #pragma unroll
        for (int r = 0; r < 2; ++r) {
            int idx = r * 256 + t, row = idx >> 3, seg = idx & 7;
            vb[r] = *(const s16x8*)(p.WehT + (size_t)(n0 + row) * 1024 + koff + k0 + seg * 8);
        }
        __syncthreads();
        #pragma unroll
        for (int r = 0; r < 4; ++r) {
            int idx = r * 256 + t, row = idx >> 3, seg = idx & 7;
            *(s16x8*)(&sh.As[row][seg * 8]) = va[r];
        }
        #pragma unroll
        for (int r = 0; r < 2; ++r) {
            int idx = r * 256 + t, row = idx >> 3, seg = idx & 7;
            *(s16x8*)(&sh.Bs[row][seg * 8]) = vb[r];
        }
        __syncthreads();
        #pragma unroll
        for (int kk = 0; kk < 64; kk += 32) {
            s16x8 af[2], bf[4];
            af[0] = *(const s16x8*)(&sh.As[wave * 32 + lrow][kk + kq * 8]);
            af[1] = *(const s16x8*)(&sh.As[wave * 32 + 16 + lrow][kk + kq * 8]);
            #pragma unroll
            for (int f = 0; f < 4; ++f)
                bf[f] = *(const s16x8*)(&sh.Bs[f * 16 + lrow][kk + kq * 8]);
            #pragma unroll
            for (int m2 = 0; m2 < 2; ++m2)
                #pragma unroll
                for (int n2 = 0; n2 < 4; ++n2)
                    acc[m2][n2] = __builtin_amdgcn_mfma_f32_16x16x32_bf16(af[m2], bf[n2], acc[m2][n2], 0, 0, 0);
        }
    }
    #pragma unroll
    for (int m2 = 0; m2 < 2; ++m2)
        #pragma unroll
        for (int n2 = 0; n2 < 4; ++n2) {
            int col = n0 + n2 * 16 + lrow;
            float bvv = addb ? p.bcat[col] : 0.0f;
            #pragma unroll
            for (int j = 0; j < 4; ++j) {
                int row = m0 + wave * 32 + m2 * 16 + kq * 4 + j;
                gpp[(size_t)row * 2048 + col] = (short)f2b(acc[m2][n2][j] + bvv);
            }
        }
}

// ---------------- final gate GEMM (K=512, ctx) + GpA + GpB + fused LSTM ----------------
__device__ __forceinline__ void fgate_phase(const P& p, GateS& sh, int bid, int step)
{
    const int t = threadIdx.x, lane = t & 63, wave = t >> 6;
    const int wr = wave >> 1, wc = wave & 1;
    const int lrow = lane & 15, kq = lane >> 4;
    const int srow = t >> 3, sseg = t & 7;
    const int m0 = (bid >> 5) * 64, n0 = (bid & 31) * 64;
    f32x4 acc[2][2] = {};
    for (int k0 = 0; k0 < 512; k0 += 64) {
        s16x8 va0 = *(const s16x8*)(p.ctxb + (size_t)(m0 + srow) * 512 + k0 + sseg * 8);
        s16x8 va1 = *(const s16x8*)(p.ctxb + (size_t)(m0 + srow + 32) * 512 + k0 + sseg * 8);
        s16x8 vb0 = *(const s16x8*)(p.WctxT + (size_t)(n0 + srow) * 512 + k0 + sseg * 8);
        s16x8 vb1 = *(const s16x8*)(p.WctxT + (size_t)(n0 + srow + 32) * 512 + k0 + sseg * 8);
        __syncthreads();
        *(s16x8*)(&sh.As[srow][sseg * 8]) = va0;
        *(s16x8*)(&sh.As[srow + 32][sseg * 8]) = va1;
        *(s16x8*)(&sh.Bs[srow][sseg * 8]) = vb0;
        *(s16x8*)(&sh.Bs[srow + 32][sseg * 8]) = vb1;
        __syncthreads();
        #pragma unroll
        for (int kk = 0; kk < 64; kk += 32) {
            s16x8 af0 = *(const s16x8*)(&sh.As[wr * 32 + lrow][kk + kq * 8]);
            s16x8 af1 = *(const s16x8*)(&sh.As[wr * 32 + 16 + lrow][kk + kq * 8]);
            s16x8 bf0 = *(const s16x8*)(&sh.Bs[wc * 32 + lrow][kk + kq * 8]);
            s16x8 bf1 = *(const s16x8*)(&sh.Bs[wc * 32 + 16 + lrow][kk + kq * 8]);
            acc[0][0] = __builtin_amdgcn_mfma_f32_16x16x32_bf16(af0, bf0, acc[0][0], 0, 0, 0);
            acc[0][1] = __builtin_amdgcn_mfma_f32_16x16x32_bf16(af0, bf1, acc[0][1], 0, 0, 0);
            acc[1][0] = __builtin_amdgcn_mfma_f32_16x16x32_bf16(af1, bf0, acc[1][0], 0, 0, 0);
            acc[1][1] = __builtin_amdgcn_mfma_f32_16x16x32_bf16(af1, bf1, acc[1][1], 0, 0, 0);
        }
    }
    #pragma unroll
    for (int m2 = 0; m2 < 2; ++m2)
        #pragma unroll
        for (int n2 = 0; n2 < 2; ++n2) {
            int cl = wc * 32 + n2 * 16 + lrow;
            #pragma unroll
            for (int j = 0; j < 4; ++j) {
                int rl = wr * 32 + m2 * 16 + kq * 4 + j;
                size_t gidx = (size_t)(m0 + rl) * 2048 + n0 + cl;
                sh.gt[rl][cl] = acc[m2][n2][j]
                              + b2f((unsigned short)p.gpA[gidx])
                              + b2f((unsigned short)p.gpB[gidx]);
            }
        }
    __syncthreads();
    const int rl4 = t >> 4, dl = t & 15;
    #pragma unroll
    for (int pass = 0; pass < 4; ++pass) {
        int row = pass * 16 + rl4;
        int b = m0 + row;
        int d = (n0 >> 2) + dl;
        float gi = sh.gt[row][dl * 4 + 0];
        float gf = sh.gt[row][dl * 4 + 1];
        float gg = sh.gt[row][dl * 4 + 2];
        float go = sh.gt[row][dl * 4 + 3];
        float cv = p.cst[(size_t)b * D_ + d];
        float c2 = sigm(gf) * cv + sigm(gi) * tanh_fast(gg);
        float h2 = sigm(go) * tanh_fast(c2);
        p.cst[(size_t)b * D_ + d] = c2;
        p.hcbf[(size_t)b * D_ + d] = (short)f2b(h2 + c2);
        p.h2bf[(size_t)b * D_ + d] = (short)f2b(h2);
        p.xeh[(size_t)b * 1024 + 512 + d] = (short)f2b(h2);
        int tok = p.target[b * T_ + step];
        p.xeh[(size_t)b * 1024 + d] = (short)f2b(p.E[(size_t)tok * D_ + d]);
    }
}

// ---------------- q GEMM 64x32 tiles -> bf16 q ----------------
__device__ __forceinline__ void q_phase(const P& p, OutS& sh, int bid)
{
    const int t = threadIdx.x, lane = t & 63, wave = t >> 6;
    const int lrow = lane & 15, kq = lane >> 4;
    const int srow = t >> 3, sseg = t & 7;
    const int m0 = (bid >> 4) * 64, n0 = (bid & 15) * 32;
    f32x4 acc0 = {}, acc1 = {};
    for (int k0 = 0; k0 < 512; k0 += 64) {
        s16x8 va0 = *(const s16x8*)(p.hcbf + (size_t)(m0 + srow) * 512 + k0 + sseg * 8);
        s16x8 va1 = *(const s16x8*)(p.hcbf + (size_t)(m0 + srow + 32) * 512 + k0 + sseg * 8);
        int brow = n0 + (srow & 31);
        s16x8 vb0 = *(const s16x8*)(p.WaT + (size_t)brow * 512 + k0 + sseg * 8);
        __syncthreads();
        *(s16x8*)(&sh.As[srow][sseg * 8]) = va0;
        *(s16x8*)(&sh.As[srow + 32][sseg * 8]) = va1;
        if (srow < 32) *(s16x8*)(&sh.Bs[srow][sseg * 8]) = vb0;
        __syncthreads();
        #pragma unroll
        for (int kk = 0; kk < 64; kk += 32) {
            s16x8 af  = *(const s16x8*)(&sh.As[wave * 16 + lrow][kk + kq * 8]);
            s16x8 bf0 = *(const s16x8*)(&sh.Bs[lrow][kk + kq * 8]);
            s16x8 bf1 = *(const s16x8*)(&sh.Bs[16 + lrow][kk + kq * 8]);
            acc0 = __builtin_amdgcn_mfma_f32_16x16x32_bf16(af, bf0, acc0, 0, 0, 0);
            acc1 = __builtin_amdgcn_mfma_f32_16x16x32_bf16(af, bf1, acc1, 0, 0, 0);
        }
    }
    #pragma unroll
    for (int n2 = 0; n2 < 2; ++n2) {
        int col = n0 + n2 * 16 + lrow;
        float bvv = p.ba[col];
        f32x4 av = n2 ? acc1 : acc0;
        #pragma unroll
        for (int j = 0; j < 4; ++j) {
            int row = m0 + wave * 16 + kq * 4 + j;
            p.qbf[(size_t)row * 512 + col] = (short)f2b(av[j] + bvv);
        }
    }
}

// ---------------- out GEMM (M=512,N=128,K=512) + fused log_softmax ----------------
__device__ __forceinline__ void out_phase(const P& p, OutS& sh, int obid, int step)
{
    const int t = threadIdx.x, lane = t & 63, wave = t >> 6;
    const int lrow = lane & 15, kq = lane >> 4;
    const int srow = t >> 3, sseg = t & 7;
    const int m0 = obid * 64;
    f32x4 acc[8] = {};
    for (int k0 = 0; k0 < 512; k0 += 64) {
        s16x8 va0 = *(const s16x8*)(p.h2bf + (size_t)(m0 + srow) * 512 + k0 + sseg * 8);
        s16x8 va1 = *(const s16x8*)(p.h2bf + (size_t)(m0 + srow + 32) * 512 + k0 + sseg * 8);
        s16x8 vb[4];
        #pragma unroll
        for (int p4 = 0; p4 < 4; ++p4)
            vb[p4] = *(const s16x8*)(p.WoutT + (size_t)(srow + p4 * 32) * 512 + k0 + sseg * 8);
        __syncthreads();
        *(s16x8*)(&sh.As[srow][sseg * 8]) = va0;
        *(s16x8*)(&sh.As[srow + 32][sseg * 8]) = va1;
        #pragma unroll
        for (int p4 = 0; p4 < 4; ++p4) *(s16x8*)(&sh.Bs[srow + p4 * 32][sseg * 8]) = vb[p4];
        __syncthreads();
        #pragma unroll
        for (int kk = 0; kk < 64; kk += 32) {
            s16x8 a = *(const s16x8*)(&sh.As[wave * 16 + lrow][kk + kq * 8]);
            #pragma unroll
            for (int f = 0; f < 8; ++f) {
                s16x8 b = *(const s16x8*)(&sh.Bs[f * 16 + lrow][kk + kq * 8]);
                acc[f] = __builtin_amdgcn_mfma_f32_16x16x32_bf16(a, b, acc[f], 0, 0, 0);
            }
        }
    }
    float colb[8];
    #pragma unroll
    for (int f = 0; f < 8; ++f) colb[f] = p.bout[f * 16 + lrow];
    #pragma unroll
    for (int j = 0; j < 4; ++j) {
        float v[8]; float mx = -1e30f;
        #pragma unroll
        for (int f = 0; f < 8; ++f) { v[f] = acc[f][j] + colb[f]; mx = fmaxf(mx, v[f]); }
        #pragma unroll
        for (int o = 1; o < 16; o <<= 1) mx = fmaxf(mx, __shfl_xor(mx, o));
        float sum = 0.f;
        #pragma unroll
        for (int f = 0; f < 8; ++f) sum += __expf(v[f] - mx);
        #pragma unroll
        for (int o = 1; o < 16; o <<= 1) sum += __shfl_xor(sum, o);
        float lse = mx + __logf(sum);
        int row = m0 + wave * 16 + kq * 4 + j;
        float* orow = p.out_logits + ((size_t)row * T_ + step) * V_;
        #pragma unroll
        for (int f = 0; f < 8; ++f) orow[f * 16 + lrow] = v[f] - lse;
    }
}

// ---------------- per-step dispatches ----------------
// A: attn only, exactly 512 blocks (2/CU, no tail)
__global__ __launch_bounds__(256, 2) void kA(P p, int step) {
    __shared__ AttnS sh;
    attn_phase(p, sh, blockIdx.x, step);
}
__global__ __launch_bounds__(256, 2) void kB(P p, int step) {
    __shared__ GateS sh;
    fgate_phase(p, sh, blockIdx.x, step);
}
// C: q(0..127) | pgateA(128..255) | pgateB(256..383) | out(384..391)
template<bool INIT>
__global__ __launch_bounds__(256, 2) void kC(P p, int step) {
    __shared__ SharedC sh;
    const int bid = blockIdx.x;
    if (bid < 128)       q_phase(p, sh.o, bid);
    else if (bid < 256)  pgate_phase(p, sh.g, bid - 128, 0,   p.gpA, true);
    else if (bid < 384)  pgate_phase(p, sh.g, bid - 256, 512, p.gpB, false);
    else if (!INIT)      out_phase(p, sh.o, bid - 384, step);
}

// ---------------- precompute kernels ----------------
__global__ __launch_bounds__(256)
void gemm64(const short* __restrict__ A, const short* __restrict__ Bt,
            const float* __restrict__ bias, short* __restrict__ Cp,
            int M, int N, int K)
{
    __shared__ __align__(16) short As[64][LDW];
    __shared__ __align__(16) short Bs[64][LDW];
    const int t = threadIdx.x;
    const int lane = t & 63, wave = t >> 6;
    const int wr = wave >> 1, wc = wave & 1;
    const int lrow = lane & 15, kq = lane >> 4;
    const int m0 = blockIdx.y * 64, n0 = blockIdx.x * 64;
    const int srow = t >> 3, sseg = t & 7;
    f32x4 acc[2][2] = {};
    for (int k0 = 0; k0 < K; k0 += 64) {
        s16x8 va0 = *(const s16x8*)(A + (size_t)(m0 + srow) * K + k0 + sseg * 8);
        s16x8 va1 = *(const s16x8*)(A + (size_t)(m0 + srow + 32) * K + k0 + sseg * 8);
        s16x8 vb0 = *(const s16x8*)(Bt + (size_t)(n0 + srow) * K + k0 + sseg * 8);
        s16x8 vb1 = *(const s16x8*)(Bt + (size_t)(n0 + srow + 32) * K + k0 + sseg * 8);
        __syncthreads();
        *(s16x8*)(&As[srow][sseg * 8]) = va0;
        *(s16x8*)(&As[srow + 32][sseg * 8]) = va1;
        *(s16x8*)(&Bs[srow][sseg * 8]) = vb0;
        *(s16x8*)(&Bs[srow + 32][sseg * 8]) = vb1;
        __syncthreads();
        for (int kk = 0; kk < 64; kk += 32) {
            s16x8 af[2], bf[2];
            af[0] = *(const s16x8*)(&As[wr * 32 + lrow][kk + kq * 8]);
            af[1] = *(const s16x8*)(&As[wr * 32 + 16 + lrow][kk + kq * 8]);
            bf[0] = *(const s16x8*)(&Bs[wc * 32 + lrow][kk + kq * 8]);
            bf[1] = *(const s16x8*)(&Bs[wc * 32 + 16 + lrow][kk + kq * 8]);
            for (int m2 = 0; m2 < 2; ++m2)
                for (int n2 = 0; n2 < 2; ++n2)
                    acc[m2][n2] = __builtin_amdgcn_mfma_f32_16x16x32_bf16(af[m2], bf[n2], acc[m2][n2], 0, 0, 0);
        }
    }
    for (int m2 = 0; m2 < 2; ++m2)
        for (int n2 = 0; n2 < 2; ++n2) {
            int col = n0 + wc * 32 + n2 * 16 + lrow;
            float bvv = bias ? bias[col] : 0.0f;
            for (int j = 0; j < 4; ++j) {
                int row = m0 + wr * 32 + m2 * 16 + kq * 4 + j;
                Cp[(size_t)row * N + col] = (short)f2b(acc[m2][n2][j] + bvv);
            }
        }
}

// kpb[b][s][d] (bf16) -> kp8[b][g=d/16][s][16B] (fp8)
__global__ __launch_bounds__(256)
void transpose_kp8(const short* __restrict__ in, unsigned char* __restrict__ out)
{
    const int b = blockIdx.x, t = threadIdx.x;
    const size_t ibase = (size_t)b * (S_ * D_);
    for (int k = t; k < 32 * S_; k += 256) {
        int g = k >> 7, s = k & 127;
        const short* src = in + ibase + (size_t)s * D_ + g * 16;
        unsigned w[4];
        #pragma unroll
        for (int q4 = 0; q4 < 4; ++q4) {
            w[q4] = pk_fp8(b2f((unsigned short)src[q4 * 4 + 0]), b2f((unsigned short)src[q4 * 4 + 1]),
                           b2f((unsigned short)src[q4 * 4 + 2]), b2f((unsigned short)src[q4 * 4 + 3]));
        }
        uint4 o; o.x = w[0]; o.y = w[1]; o.z = w[2]; o.w = w[3];
        *(uint4*)(out + ibase + ((size_t)g * S_ + s) * 16) = o;
    }
}

__global__ __launch_bounds__(256)
void cast_fp8_v4(const float* __restrict__ in, unsigned char* __restrict__ out, int n4)
{
    int i = blockIdx.x * 256 + threadIdx.x;
    int stride = gridDim.x * 256;
    for (; i < n4; i += stride) {
        f32x4 v = ((const f32x4*)in)[i];
        ((unsigned*)out)[i] = pk_fp8(v[0], v[1], v[2], v[3]);
    }
}

__global__ __launch_bounds__(256)
void init_state(const float* __restrict__ e_h, const float* __restrict__ e_c,
                float* __restrict__ c, short* __restrict__ hcbf,
                short* __restrict__ xeh, const float* __restrict__ E)
{
    int gid = blockIdx.x * 256 + threadIdx.x;
    int b = gid >> 9, d = gid & 511;
    float h0 = e_h[gid], c0 = e_c[gid];
    c[gid] = c0;
    hcbf[gid] = (short)f2b(h0 + c0);
    xeh[(size_t)b * 1024 + 512 + d] = (short)f2b(h0);
    xeh[(size_t)b * 1024 + d] = (short)f2b(E[d]);   // token 0 (SOS)
}

__global__ __launch_bounds__(256)
void transpose_cast(const float* __restrict__ in, short* __restrict__ out,
                    int N, int ostride, int koff, int gate_perm)
{
    __shared__ float tile[64][65];
    int t = threadIdx.x;
    int n0 = blockIdx.x * 64, k0 = blockIdx.y * 64;
    int cc = t & 63, r4 = t >> 6;
    for (int i = 0; i < 16; ++i) {
        int r = i * 4 + r4;
        tile[r][cc] = in[(size_t)(k0 + r) * N + n0 + cc];
    }
    __syncthreads();
    for (int i = 0; i < 16; ++i) {
        int nr = i * 4 + r4;
        int ng = n0 + nr;
        int np = gate_perm ? ((ng & 511) * 4 + (ng >> 9)) : ng;
        out[(size_t)np * ostride + koff + k0 + cc] = (short)f2b(tile[cc][nr]);
    }
}

__global__ __launch_bounds__(256)
void cast_bf16_v4(const float* __restrict__ in, short* __restrict__ out, int n4)
{
    int i = blockIdx.x * 256 + threadIdx.x;
    int stride = gridDim.x * 256;
    for (; i < n4; i += stride) {
        f32x4 v = ((const f32x4*)in)[i];
        s16x4 o;
        for (int j = 0; j < 4; ++j) o[j] = (short)f2b(v[j]);
        ((s16x4*)out)[i] = o;
    }
}

__global__ __launch_bounds__(256)
void make_bcat(const float* __restrict__ b_ih, const float* __restrict__ b_hh, float* __restrict__ bcat)
{
    int i = blockIdx.x * 256 + threadIdx.x;
    if (i < 2048) {
        int np = (i & 511) * 4 + (i >> 9);
        bcat[np] = b_ih[i] + b_hh[i];
    }
}

extern "C" void kernel_launch(void* const* d_in, const int* in_sizes, int n_in,
                              void* d_out, int out_size, void* d_ws, size_t ws_size,
                              hipStream_t stream)
{
    const float* e_all  = (const float*)d_in[0];
    const float* e_h    = (const float*)d_in[1];
    const float* e_c    = (const float*)d_in[2];
    const int*   target = (const int*)d_in[3];
    const float* E      = (const float*)d_in[4];
    const float* Wa     = (const float*)d_in[5];
    const float* ba     = (const float*)d_in[6];
    const float* Ua     = (const float*)d_in[7];
    const float* bu     = (const float*)d_in[8];
    const float* Va     = (const float*)d_in[9];
    const float* bv     = (const float*)d_in[10];
    const float* W_ih   = (const float*)d_in[11];
    const float* b_ih   = (const float*)d_in[12];
    const float* W_hh   = (const float*)d_in[13];
    const float* b_hh   = (const float*)d_in[14];
    const float* W_out  = (const float*)d_in[15];
    const float* b_out  = (const float*)d_in[16];

    char* ws = (char*)d_ws;
    size_t off = 0;
    auto alloc = [&](size_t bytes) { void* p = ws + off; off += (bytes + 255) & ~255ull; return p; };
    short* ealb  = (short*)alloc((size_t)B_ * S_ * D_ * 2);
    short* kpb   = (short*)alloc((size_t)B_ * S_ * D_ * 2);          // bf16 scratch (pre-fp8)
    unsigned char* kp8 = (unsigned char*)alloc((size_t)B_ * S_ * D_); // fp8 [b][d/16][s][16]
    unsigned char* ea8 = (unsigned char*)alloc((size_t)B_ * S_ * D_); // fp8 [b][s][d]
    short* WaT   = (short*)alloc((size_t)D_ * D_ * 2);
    short* UaT   = (short*)alloc((size_t)D_ * D_ * 2);
    short* WehT  = (short*)alloc((size_t)2048 * 1024 * 2);
    short* WctxT = (short*)alloc((size_t)2048 * 512 * 2);
    short* WoutT = (short*)alloc((size_t)V_ * D_ * 2);
    float* bcat  = (float*)alloc(2048 * 4);
    short* qbf   = (short*)alloc((size_t)B_ * D_ * 2);
    short* vab   = (short*)alloc((size_t)D_ * 2);
    short* xeh   = (short*)alloc((size_t)B_ * 1024 * 2);
    short* ctxb  = (short*)alloc((size_t)B_ * D_ * 2);
    short* gpA   = (short*)alloc((size_t)B_ * 2048 * 2);
    short* gpB   = (short*)alloc((size_t)B_ * 2048 * 2);
    short* hcbf  = (short*)alloc((size_t)B_ * D_ * 2);
    short* h2bf  = (short*)alloc((size_t)B_ * D_ * 2);
    float* cst   = (float*)alloc((size_t)B_ * D_ * 4);
    if (off > ws_size) return;

    float* out_logits = (float*)d_out;                        // [B,T,V]
    float* out_attn   = (float*)d_out + (size_t)B_ * T_ * V_; // [B,T,S]

    // ---- precompute ----
    cast_bf16_v4<<<4096, 256, 0, stream>>>(e_all, ealb, B_ * S_ * D_ / 4);
    cast_fp8_v4<<<4096, 256, 0, stream>>>(e_all, ea8, B_ * S_ * D_ / 4);
    cast_bf16_v4<<<1,    256, 0, stream>>>(Va, vab, D_ / 4);
    transpose_cast<<<dim3(8, 8),  256, 0, stream>>>(Wa,  WaT,  512,  512, 0, 0);
    transpose_cast<<<dim3(8, 8),  256, 0, stream>>>(Ua,  UaT,  512,  512, 0, 0);
    transpose_cast<<<dim3(32, 8), 256, 0, stream>>>(W_ih,              WehT,  2048, 1024, 0,   1);
    transpose_cast<<<dim3(32, 8), 256, 0, stream>>>(W_ih + 512 * 2048, WctxT, 2048, 512,  0,   1);
    transpose_cast<<<dim3(32, 8), 256, 0, stream>>>(W_hh,              WehT,  2048, 1024, 512, 1);
    transpose_cast<<<dim3(2, 8),  256, 0, stream>>>(W_out, WoutT, 128, 512, 0, 0);
    make_bcat<<<8, 256, 0, stream>>>(b_ih, b_hh, bcat);
    gemm64<<<dim3(8, 1024), 256, 0, stream>>>(ealb, UaT, bu, kpb, B_ * S_, 512, 512);
    transpose_kp8<<<512, 256, 0, stream>>>(kpb, kp8);
    init_state<<<1024, 256, 0, stream>>>(e_h, e_c, cst, hcbf, xeh, E);

    P pp;
    pp.target = target; pp.E = E; pp.bv = bv; pp.ba = ba; pp.bout = b_out;
    pp.vab = vab;
    pp.ea8 = ea8; pp.kp8 = kp8; pp.WaT = WaT; pp.WehT = WehT; pp.WctxT = WctxT; pp.WoutT = WoutT;
    pp.bcat = bcat; pp.qbf = qbf; pp.xeh = xeh; pp.ctxb = ctxb; pp.gpA = gpA; pp.gpB = gpB;
    pp.hcbf = hcbf; pp.h2bf = h2bf; pp.cst = cst;
    pp.out_logits = out_logits; pp.out_attn = out_attn;

    // q(0) + gp(0) from initial state
    kC<true><<<384, 256, 0, stream>>>(pp, 0);

    // ---- sequential decode: A(attn) -> B(fgate+LSTM) -> C(q ∥ pgateA ∥ pgateB ∥ out) ----
    for (int t = 0; t < T_; ++t) {
        kA<<<512, 256, 0, stream>>>(pp, t);
        kB<<<256, 256, 0, stream>>>(pp, t);
        kC<false><<<392, 256, 0, stream>>>(pp, t);
    }
    (void)n_in; (void)in_sizes; (void)out_size;
}